// Round 1
// baseline (2113.274 us; speedup 1.0000x reference)
//
#include <hip/hip_runtime.h>

#define DIM 128
#define NWORD 100000
#define NTOPIC 10000
#define NDOC 50000

// ---------------------------------------------------------------------------
// compose1:
//   blocks 0..127   : A[r][j]     = sum_m W_wd[r,m] * W_wt[m,j]       (A = W_wd@W_wt)
//   blocks 128..255 : WcT_t[k][j] = sum_m W_tt[j,m] * W_td[m,k]       (Wc_t = W_tt@W_td, stored transposed)
//   block 256       : tmpb[j]     = sum_m W_wt[j,m] * b_ww[m] + b_wt[j]
//   block 257       : c_t[j]      = sum_m W_tt[j,m] * b_td[m] + b_tt[j]
// ---------------------------------------------------------------------------
__global__ void compose1(const float* __restrict__ W_ww, const float* __restrict__ b_ww,
                         const float* __restrict__ W_wt, const float* __restrict__ b_wt,
                         const float* __restrict__ W_wd, const float* __restrict__ b_wd,
                         const float* __restrict__ W_td, const float* __restrict__ b_td,
                         const float* __restrict__ W_tt, const float* __restrict__ b_tt,
                         float* __restrict__ A, float* __restrict__ WcT_t,
                         float* __restrict__ tmpb, float* __restrict__ c_t)
{
    int b = blockIdx.x, j = threadIdx.x;
    if (b < 128) {
        float s = 0.f;
        for (int m = 0; m < 128; ++m) s = fmaf(W_wd[b * 128 + m], W_wt[m * 128 + j], s);
        A[b * 128 + j] = s;
    } else if (b < 256) {
        int k = b - 128;
        float s = 0.f;
        for (int m = 0; m < 128; ++m) s = fmaf(W_tt[j * 128 + m], W_td[m * 128 + k], s);
        WcT_t[k * 128 + j] = s;
    } else if (b == 256) {
        float s = b_wt[j];
        for (int m = 0; m < 128; ++m) s = fmaf(W_wt[j * 128 + m], b_ww[m], s);
        tmpb[j] = s;
    } else {
        float s = b_tt[j];
        for (int m = 0; m < 128; ++m) s = fmaf(W_tt[j * 128 + m], b_td[m], s);
        c_t[j] = s;
    }
}

// ---------------------------------------------------------------------------
// compose2:
//   blocks 0..127 (b=k): WcT_w[k][j] = sum_m A[j,m] * W_ww[m,k]   (Wc_w = A@W_ww, transposed store)
//   block 128          : c_w[j] = sum_m W_wd[j,m]*tmpb[m] + b_wd[j]
// ---------------------------------------------------------------------------
__global__ void compose2(const float* __restrict__ W_ww, const float* __restrict__ W_wd,
                         const float* __restrict__ b_wd, const float* __restrict__ A,
                         const float* __restrict__ tmpb,
                         float* __restrict__ WcT_w, float* __restrict__ c_w)
{
    int b = blockIdx.x, j = threadIdx.x;
    if (b < 128) {
        int k = b;
        float s = 0.f;
        for (int m = 0; m < 128; ++m) s = fmaf(A[j * 128 + m], W_ww[m * 128 + k], s);
        WcT_w[k * 128 + j] = s;
    } else {
        float s = b_wd[j];
        for (int m = 0; m < 128; ++m) s = fmaf(W_wd[j * 128 + m], tmpb[m], s);
        c_w[j] = s;
    }
}

// ---------------------------------------------------------------------------
// transform: y[row] = x[row] @ Wc^T + c     (WT is k-major: WT[k*128+j] = Wc[j,k])
// 256 threads = 4 waves, one row per wave per iteration.
// WT staged in LDS (64KB, lane-consecutive reads -> conflict-free).
// x row broadcast via __shfl from 2 registers.
// ---------------------------------------------------------------------------
__global__ void transform(const float* __restrict__ x, const float* __restrict__ WT,
                          const float* __restrict__ bias, float* __restrict__ y, int nrows)
{
    __shared__ float wt[128 * 128];
    for (int i = threadIdx.x; i < 128 * 32; i += 256)
        reinterpret_cast<float4*>(wt)[i] = reinterpret_cast<const float4*>(WT)[i];
    __syncthreads();

    const int wave = threadIdx.x >> 6, lane = threadIdx.x & 63;
    const float b0 = bias[lane], b1 = bias[lane + 64];

    for (int row = blockIdx.x * 4 + wave; row < nrows; row += gridDim.x * 4) {
        float xv0 = x[(size_t)row * 128 + lane];
        float xv1 = x[(size_t)row * 128 + 64 + lane];
        float acc0 = b0, acc1 = b1;
#pragma unroll
        for (int k = 0; k < 64; ++k) {
            float xk = __shfl(xv0, k);
            acc0 = fmaf(xk, wt[k * 128 + lane], acc0);
            acc1 = fmaf(xk, wt[k * 128 + 64 + lane], acc1);
        }
#pragma unroll
        for (int k = 0; k < 64; ++k) {
            float xk = __shfl(xv1, k);
            acc0 = fmaf(xk, wt[(k + 64) * 128 + lane], acc0);
            acc1 = fmaf(xk, wt[(k + 64) * 128 + 64 + lane], acc1);
        }
        y[(size_t)row * 128 + lane] = acc0;
        y[(size_t)row * 128 + 64 + lane] = acc1;
    }
}

// ---------------------------------------------------------------------------
// agg: one (edge, dim) per thread. sum[dst] += h[src]*ew ; cnt[dst] += 1
// ---------------------------------------------------------------------------
__global__ void agg(const float* __restrict__ h, const int* __restrict__ src,
                    const int* __restrict__ dst, const float* __restrict__ ew,
                    float* __restrict__ sum, float* __restrict__ cnt, int nedges)
{
    int idx = blockIdx.x * blockDim.x + threadIdx.x;
    int e = idx >> 7, d = idx & 127;
    if (e >= nedges) return;
    int s = src[e], t = dst[e];
    float w = ew[e];
    float v = h[(size_t)s * 128 + d] * w;
    atomicAdd(&sum[(size_t)t * 128 + d], v);
    if (d == 0) atomicAdd(&cnt[t], 1.0f);
}

// ---------------------------------------------------------------------------
// finalize: per-node mean(s) + cross-relation sum + relu, in place on d_out
// ---------------------------------------------------------------------------
__global__ void finalize(float* __restrict__ out,
                         const float* __restrict__ sum_tt, const float* __restrict__ sum_td,
                         const float* __restrict__ cnt_ww, const float* __restrict__ cnt_wt,
                         const float* __restrict__ cnt_tt, const float* __restrict__ cnt_wd,
                         const float* __restrict__ cnt_td)
{
    int idx = blockIdx.x * blockDim.x + threadIdx.x;
    int n = idx >> 7, d = idx & 127;
    if (n >= NWORD + NTOPIC + NDOC) return;
    float v;
    if (n < NWORD) {
        v = out[idx] / fmaxf(cnt_ww[n], 1.0f);
    } else if (n < NWORD + NTOPIC) {
        int i = n - NWORD;
        v = out[idx] / fmaxf(cnt_wt[i], 1.0f) + sum_tt[i * 128 + d] / fmaxf(cnt_tt[i], 1.0f);
    } else {
        int i = n - NWORD - NTOPIC;
        v = out[idx] / fmaxf(cnt_wd[i], 1.0f) + sum_td[i * 128 + d] / fmaxf(cnt_td[i], 1.0f);
    }
    out[idx] = fmaxf(v, 0.0f);
}

extern "C" void kernel_launch(void* const* d_in, const int* in_sizes, int n_in,
                              void* d_out, int out_size, void* d_ws, size_t ws_size,
                              hipStream_t stream) {
    const float* h_word  = (const float*)d_in[0];
    const float* h_topic = (const float*)d_in[1];
    // d_in[2] = h_doc: unused (doc nodes only receive messages)
    const float* W_ww = (const float*)d_in[3];  const float* b_ww = (const float*)d_in[4];
    const float* W_wt = (const float*)d_in[5];  const float* b_wt = (const float*)d_in[6];
    const float* W_wd = (const float*)d_in[7];  const float* b_wd = (const float*)d_in[8];
    const float* W_td = (const float*)d_in[9];  const float* b_td = (const float*)d_in[10];
    const float* W_tt = (const float*)d_in[11]; const float* b_tt = (const float*)d_in[12];
    const int*   src_ww = (const int*)d_in[13]; const int* dst_ww = (const int*)d_in[14];
    const float* ew_ww  = (const float*)d_in[15];
    const int*   src_wt = (const int*)d_in[16]; const int* dst_wt = (const int*)d_in[17];
    const float* ew_wt  = (const float*)d_in[18];
    const int*   src_wd = (const int*)d_in[19]; const int* dst_wd = (const int*)d_in[20];
    const float* ew_wd  = (const float*)d_in[21];
    const int*   src_td = (const int*)d_in[22]; const int* dst_td = (const int*)d_in[23];
    const float* ew_td  = (const float*)d_in[24];
    const int*   src_tt = (const int*)d_in[25]; const int* dst_tt = (const int*)d_in[26];
    const float* ew_tt  = (const float*)d_in[27];

    const int E_ww = 200000, E_wt = 100000, E_wd = 150000, E_td = 100000, E_tt = 50000;

    float* out = (float*)d_out;
    float* ws  = (float*)d_ws;

    // workspace layout (floats)
    float* hw     = ws;                          // NWORD*128  = 12,800,000
    float* ht     = hw + (size_t)NWORD * 128;    // NTOPIC*128 =  1,280,000
    float* WcT_w  = ht + (size_t)NTOPIC * 128;   // 16384
    float* c_w    = WcT_w + 16384;               // 128
    float* WcT_t  = c_w + 128;                   // 16384
    float* c_t    = WcT_t + 16384;               // 128
    float* Amat   = c_t + 128;                   // 16384
    float* tmpb   = Amat + 16384;                // 128
    // zero-initialized region:
    float* sum_tt = tmpb + 128;                  // NTOPIC*128
    float* sum_td = sum_tt + (size_t)NTOPIC * 128; // NDOC*128
    float* cnt_ww = sum_td + (size_t)NDOC * 128; // NWORD
    float* cnt_wt = cnt_ww + NWORD;              // NTOPIC
    float* cnt_tt = cnt_wt + NTOPIC;             // NTOPIC
    float* cnt_wd = cnt_tt + NTOPIC;             // NDOC
    float* cnt_td = cnt_wd + NDOC;               // NDOC
    float* zend   = cnt_td + NDOC;

    // sum regions living directly in d_out
    float* sum_ww = out;                               // word rows
    float* sum_wt = out + (size_t)NWORD * 128;         // topic rows
    float* sum_wd = out + (size_t)(NWORD + NTOPIC) * 128; // doc rows

    size_t out_bytes = (size_t)(NWORD + NTOPIC + NDOC) * 128 * sizeof(float);
    hipMemsetAsync(d_out, 0, out_bytes, stream);
    hipMemsetAsync(sum_tt, 0, (size_t)(zend - sum_tt) * sizeof(float), stream);

    compose1<<<258, 128, 0, stream>>>(W_ww, b_ww, W_wt, b_wt, W_wd, b_wd, W_td, b_td,
                                      W_tt, b_tt, Amat, WcT_t, tmpb, c_t);
    compose2<<<129, 128, 0, stream>>>(W_ww, W_wd, b_wd, Amat, tmpb, WcT_w, c_w);

    transform<<<1024, 256, 0, stream>>>(h_word,  WcT_w, c_w, hw, NWORD);
    transform<<<640,  256, 0, stream>>>(h_topic, WcT_t, c_t, ht, NTOPIC);

    agg<<<(E_ww * 128 + 255) / 256, 256, 0, stream>>>(hw, src_ww, dst_ww, ew_ww, sum_ww, cnt_ww, E_ww);
    agg<<<(E_wt * 128 + 255) / 256, 256, 0, stream>>>(hw, src_wt, dst_wt, ew_wt, sum_wt, cnt_wt, E_wt);
    agg<<<(E_wd * 128 + 255) / 256, 256, 0, stream>>>(hw, src_wd, dst_wd, ew_wd, sum_wd, cnt_wd, E_wd);
    agg<<<(E_td * 128 + 255) / 256, 256, 0, stream>>>(ht, src_td, dst_td, ew_td, sum_td, cnt_td, E_td);
    agg<<<(E_tt * 128 + 255) / 256, 256, 0, stream>>>(ht, src_tt, dst_tt, ew_tt, sum_tt, cnt_tt, E_tt);

    finalize<<<(NWORD + NTOPIC + NDOC) * 128 / 256, 256, 0, stream>>>(
        out, sum_tt, sum_td, cnt_ww, cnt_wt, cnt_tt, cnt_wd, cnt_td);
}

// Round 2
// 1395.429 us; speedup vs baseline: 1.5144x; 1.5144x over previous
//
#include <hip/hip_runtime.h>

#define DIM 128
#define NWORD 100000
#define NTOPIC 10000
#define NDOC 50000

// ---------------------------------------------------------------------------
// compose1:
//   blocks 0..127   : A[r][j]     = sum_m W_wd[r,m] * W_wt[m,j]       (A = W_wd@W_wt)
//   blocks 128..255 : WcT_t[k][j] = sum_m W_tt[j,m] * W_td[m,k]       (Wc_t = W_tt@W_td, stored transposed)
//   block 256       : tmpb[j]     = sum_m W_wt[j,m] * b_ww[m] + b_wt[j]
//   block 257       : c_t[j]      = sum_m W_tt[j,m] * b_td[m] + b_tt[j]
// ---------------------------------------------------------------------------
__global__ void compose1(const float* __restrict__ W_ww, const float* __restrict__ b_ww,
                         const float* __restrict__ W_wt, const float* __restrict__ b_wt,
                         const float* __restrict__ W_wd, const float* __restrict__ b_wd,
                         const float* __restrict__ W_td, const float* __restrict__ b_td,
                         const float* __restrict__ W_tt, const float* __restrict__ b_tt,
                         float* __restrict__ A, float* __restrict__ WcT_t,
                         float* __restrict__ tmpb, float* __restrict__ c_t)
{
    int b = blockIdx.x, j = threadIdx.x;
    if (b < 128) {
        float s = 0.f;
        for (int m = 0; m < 128; ++m) s = fmaf(W_wd[b * 128 + m], W_wt[m * 128 + j], s);
        A[b * 128 + j] = s;
    } else if (b < 256) {
        int k = b - 128;
        float s = 0.f;
        for (int m = 0; m < 128; ++m) s = fmaf(W_tt[j * 128 + m], W_td[m * 128 + k], s);
        WcT_t[k * 128 + j] = s;
    } else if (b == 256) {
        float s = b_wt[j];
        for (int m = 0; m < 128; ++m) s = fmaf(W_wt[j * 128 + m], b_ww[m], s);
        tmpb[j] = s;
    } else {
        float s = b_tt[j];
        for (int m = 0; m < 128; ++m) s = fmaf(W_tt[j * 128 + m], b_td[m], s);
        c_t[j] = s;
    }
}

// ---------------------------------------------------------------------------
// compose2:
//   blocks 0..127 (b=k): WcT_w[k][j] = sum_m A[j,m] * W_ww[m,k]   (Wc_w = A@W_ww, transposed store)
//   block 128          : c_w[j] = sum_m W_wd[j,m]*tmpb[m] + b_wd[j]
// ---------------------------------------------------------------------------
__global__ void compose2(const float* __restrict__ W_ww, const float* __restrict__ W_wd,
                         const float* __restrict__ b_wd, const float* __restrict__ A,
                         const float* __restrict__ tmpb,
                         float* __restrict__ WcT_w, float* __restrict__ c_w)
{
    int b = blockIdx.x, j = threadIdx.x;
    if (b < 128) {
        int k = b;
        float s = 0.f;
        for (int m = 0; m < 128; ++m) s = fmaf(A[j * 128 + m], W_ww[m * 128 + k], s);
        WcT_w[k * 128 + j] = s;
    } else {
        float s = b_wd[j];
        for (int m = 0; m < 128; ++m) s = fmaf(W_wd[j * 128 + m], tmpb[m], s);
        c_w[j] = s;
    }
}

// ---------------------------------------------------------------------------
// transform: y[row] = x[row] @ Wc^T + c     (WT is k-major: WT[k*128+j] = Wc[j,k])
// Register-tiled: 48 KB LDS (half-WT 32KB + 32-row x tile 16KB) -> 3 blocks/CU.
// thread (c = tid&63, rg = tid>>6) computes rows rg*8..rg*8+7 of column
// pass*64+c. Per k: 1 conflict-free wt read + 8 broadcast xs reads + 8 FMAs.
// ---------------------------------------------------------------------------
__global__ __launch_bounds__(256) void transform(
    const float* __restrict__ x, const float* __restrict__ WT,
    const float* __restrict__ bias, float* __restrict__ y, int nrows)
{
    __shared__ float wtp[128 * 64];   // 32 KB: columns [pass*64, pass*64+64)
    __shared__ float xs[32 * 128];    // 16 KB: 32 rows of x
    const int tid = threadIdx.x;
    const int c   = tid & 63;
    const int rg  = tid >> 6;         // 0..3 (wave id), 8 rows each

    for (int pass = 0; pass < 2; ++pass) {
        __syncthreads();  // protect wtp from previous pass readers
        for (int i = tid; i < 128 * 16; i += 256) {
            int k  = i >> 4;
            int c4 = (i & 15) << 2;
            reinterpret_cast<float4*>(wtp)[i] =
                *reinterpret_cast<const float4*>(&WT[k * 128 + pass * 64 + c4]);
        }
        const float bc = bias[pass * 64 + c];
        __syncthreads();

        for (int tile = blockIdx.x; tile * 32 < nrows; tile += gridDim.x) {
            int base = tile * 32;
            __syncthreads();  // previous tile's readers done before overwrite
            for (int i = tid; i < 1024; i += 256) {
                int r  = i >> 5;
                int kk = (i & 31) << 2;
                int row = base + r;
                float4 v = (row < nrows)
                    ? *reinterpret_cast<const float4*>(&x[(size_t)row * 128 + kk])
                    : float4{0.f, 0.f, 0.f, 0.f};
                reinterpret_cast<float4*>(xs)[i] = v;
            }
            __syncthreads();

            float acc[8];
#pragma unroll
            for (int i = 0; i < 8; ++i) acc[i] = bc;
            const float* xrow = &xs[rg * 8 * 128];
#pragma unroll 4
            for (int k = 0; k < 128; ++k) {
                float w = wtp[k * 64 + c];
#pragma unroll
                for (int i = 0; i < 8; ++i)
                    acc[i] = fmaf(xrow[i * 128 + k], w, acc[i]);
            }
#pragma unroll
            for (int i = 0; i < 8; ++i) {
                int row = base + rg * 8 + i;
                if (row < nrows) y[(size_t)row * 128 + pass * 64 + c] = acc[i];
            }
        }
    }
}

// ---------------------------------------------------------------------------
// agg: 32 threads per edge, float4 per thread.
// sum[dst] += h[src]*ew ; cnt[dst] += 1
// ---------------------------------------------------------------------------
__global__ void agg(const float* __restrict__ h, const int* __restrict__ src,
                    const int* __restrict__ dst, const float* __restrict__ ew,
                    float* __restrict__ sum, float* __restrict__ cnt, int nedges)
{
    int idx = blockIdx.x * blockDim.x + threadIdx.x;
    int e = idx >> 5, d4 = (idx & 31) << 2;
    if (e >= nedges) return;
    int s = src[e], t = dst[e];
    float w = ew[e];
    float4 v = *reinterpret_cast<const float4*>(&h[(size_t)s * 128 + d4]);
    float* sp = &sum[(size_t)t * 128 + d4];
    atomicAdd(sp + 0, v.x * w);
    atomicAdd(sp + 1, v.y * w);
    atomicAdd(sp + 2, v.z * w);
    atomicAdd(sp + 3, v.w * w);
    if (d4 == 0) atomicAdd(&cnt[t], 1.0f);
}

// ---------------------------------------------------------------------------
// finalize: per-node mean(s) + cross-relation sum + relu, in place on d_out
// ---------------------------------------------------------------------------
__global__ void finalize(float* __restrict__ out,
                         const float* __restrict__ sum_tt, const float* __restrict__ sum_td,
                         const float* __restrict__ cnt_ww, const float* __restrict__ cnt_wt,
                         const float* __restrict__ cnt_tt, const float* __restrict__ cnt_wd,
                         const float* __restrict__ cnt_td)
{
    int idx = blockIdx.x * blockDim.x + threadIdx.x;
    int n = idx >> 7, d = idx & 127;
    if (n >= NWORD + NTOPIC + NDOC) return;
    float v;
    if (n < NWORD) {
        v = out[idx] / fmaxf(cnt_ww[n], 1.0f);
    } else if (n < NWORD + NTOPIC) {
        int i = n - NWORD;
        v = out[idx] / fmaxf(cnt_wt[i], 1.0f) + sum_tt[i * 128 + d] / fmaxf(cnt_tt[i], 1.0f);
    } else {
        int i = n - NWORD - NTOPIC;
        v = out[idx] / fmaxf(cnt_wd[i], 1.0f) + sum_td[i * 128 + d] / fmaxf(cnt_td[i], 1.0f);
    }
    out[idx] = fmaxf(v, 0.0f);
}

extern "C" void kernel_launch(void* const* d_in, const int* in_sizes, int n_in,
                              void* d_out, int out_size, void* d_ws, size_t ws_size,
                              hipStream_t stream) {
    const float* h_word  = (const float*)d_in[0];
    const float* h_topic = (const float*)d_in[1];
    // d_in[2] = h_doc: unused (doc nodes only receive messages)
    const float* W_ww = (const float*)d_in[3];  const float* b_ww = (const float*)d_in[4];
    const float* W_wt = (const float*)d_in[5];  const float* b_wt = (const float*)d_in[6];
    const float* W_wd = (const float*)d_in[7];  const float* b_wd = (const float*)d_in[8];
    const float* W_td = (const float*)d_in[9];  const float* b_td = (const float*)d_in[10];
    const float* W_tt = (const float*)d_in[11]; const float* b_tt = (const float*)d_in[12];
    const int*   src_ww = (const int*)d_in[13]; const int* dst_ww = (const int*)d_in[14];
    const float* ew_ww  = (const float*)d_in[15];
    const int*   src_wt = (const int*)d_in[16]; const int* dst_wt = (const int*)d_in[17];
    const float* ew_wt  = (const float*)d_in[18];
    const int*   src_wd = (const int*)d_in[19]; const int* dst_wd = (const int*)d_in[20];
    const float* ew_wd  = (const float*)d_in[21];
    const int*   src_td = (const int*)d_in[22]; const int* dst_td = (const int*)d_in[23];
    const float* ew_td  = (const float*)d_in[24];
    const int*   src_tt = (const int*)d_in[25]; const int* dst_tt = (const int*)d_in[26];
    const float* ew_tt  = (const float*)d_in[27];

    const int E_ww = 200000, E_wt = 100000, E_wd = 150000, E_td = 100000, E_tt = 50000;

    float* out = (float*)d_out;
    float* ws  = (float*)d_ws;

    // workspace layout (floats)
    float* hw     = ws;                          // NWORD*128
    float* ht     = hw + (size_t)NWORD * 128;    // NTOPIC*128
    float* WcT_w  = ht + (size_t)NTOPIC * 128;   // 16384
    float* c_w    = WcT_w + 16384;               // 128
    float* WcT_t  = c_w + 128;                   // 16384
    float* c_t    = WcT_t + 16384;               // 128
    float* Amat   = c_t + 128;                   // 16384
    float* tmpb   = Amat + 16384;                // 128
    // zero-initialized region:
    float* sum_tt = tmpb + 128;                  // NTOPIC*128
    float* sum_td = sum_tt + (size_t)NTOPIC * 128; // NDOC*128
    float* cnt_ww = sum_td + (size_t)NDOC * 128; // NWORD
    float* cnt_wt = cnt_ww + NWORD;              // NTOPIC
    float* cnt_tt = cnt_wt + NTOPIC;             // NTOPIC
    float* cnt_wd = cnt_tt + NTOPIC;             // NDOC
    float* cnt_td = cnt_wd + NDOC;               // NDOC
    float* zend   = cnt_td + NDOC;

    // sum regions living directly in d_out
    float* sum_ww = out;                                  // word rows
    float* sum_wt = out + (size_t)NWORD * 128;            // topic rows
    float* sum_wd = out + (size_t)(NWORD + NTOPIC) * 128; // doc rows

    size_t out_bytes = (size_t)(NWORD + NTOPIC + NDOC) * 128 * sizeof(float);
    hipMemsetAsync(d_out, 0, out_bytes, stream);
    hipMemsetAsync(sum_tt, 0, (size_t)(zend - sum_tt) * sizeof(float), stream);

    compose1<<<258, 128, 0, stream>>>(W_ww, b_ww, W_wt, b_wt, W_wd, b_wd, W_td, b_td,
                                      W_tt, b_tt, Amat, WcT_t, tmpb, c_t);
    compose2<<<129, 128, 0, stream>>>(W_ww, W_wd, b_wd, Amat, tmpb, WcT_w, c_w);

    transform<<<768, 256, 0, stream>>>(h_word,  WcT_w, c_w, hw, NWORD);
    transform<<<313, 256, 0, stream>>>(h_topic, WcT_t, c_t, ht, NTOPIC);

    agg<<<(E_ww * 32 + 255) / 256, 256, 0, stream>>>(hw, src_ww, dst_ww, ew_ww, sum_ww, cnt_ww, E_ww);
    agg<<<(E_wt * 32 + 255) / 256, 256, 0, stream>>>(hw, src_wt, dst_wt, ew_wt, sum_wt, cnt_wt, E_wt);
    agg<<<(E_wd * 32 + 255) / 256, 256, 0, stream>>>(hw, src_wd, dst_wd, ew_wd, sum_wd, cnt_wd, E_wd);
    agg<<<(E_td * 32 + 255) / 256, 256, 0, stream>>>(ht, src_td, dst_td, ew_td, sum_td, cnt_td, E_td);
    agg<<<(E_tt * 32 + 255) / 256, 256, 0, stream>>>(ht, src_tt, dst_tt, ew_tt, sum_tt, cnt_tt, E_tt);

    finalize<<<(NWORD + NTOPIC + NDOC) * 128 / 256, 256, 0, stream>>>(
        out, sum_tt, sum_td, cnt_ww, cnt_wt, cnt_tt, cnt_wd, cnt_td);
}

// Round 3
// 449.499 us; speedup vs baseline: 4.7014x; 3.1044x over previous
//
#include <hip/hip_runtime.h>

#define DIM 128
#define NWORD 100000
#define NTOPIC 10000
#define NDOC 50000
#define NOUT (NWORD + NTOPIC + NDOC)

#define E_WW 200000
#define E_WT 100000
#define E_WD 150000
#define E_TD 100000
#define E_TT 50000
#define E_TOT 600000

// per-(relation,dst) counter slot bases in the concatenated space
#define B_WW 0
#define B_WT 100000
#define B_TT 110000
#define B_WD 120000
#define B_TD 170000
#define NSLOT 220000
#define NBLK_SCAN 215   // ceil(220000/1024)

// ---------------------------------------------------------------------------
// compose1 / compose2: fold the chained linears into one (W,b) per node type.
// ---------------------------------------------------------------------------
__global__ void compose1(const float* __restrict__ W_ww, const float* __restrict__ b_ww,
                         const float* __restrict__ W_wt, const float* __restrict__ b_wt,
                         const float* __restrict__ W_wd, const float* __restrict__ b_wd,
                         const float* __restrict__ W_td, const float* __restrict__ b_td,
                         const float* __restrict__ W_tt, const float* __restrict__ b_tt,
                         float* __restrict__ A, float* __restrict__ WcT_t,
                         float* __restrict__ tmpb, float* __restrict__ c_t)
{
    int b = blockIdx.x, j = threadIdx.x;
    if (b < 128) {
        float s = 0.f;
        for (int m = 0; m < 128; ++m) s = fmaf(W_wd[b * 128 + m], W_wt[m * 128 + j], s);
        A[b * 128 + j] = s;
    } else if (b < 256) {
        int k = b - 128;
        float s = 0.f;
        for (int m = 0; m < 128; ++m) s = fmaf(W_tt[j * 128 + m], W_td[m * 128 + k], s);
        WcT_t[k * 128 + j] = s;
    } else if (b == 256) {
        float s = b_wt[j];
        for (int m = 0; m < 128; ++m) s = fmaf(W_wt[j * 128 + m], b_ww[m], s);
        tmpb[j] = s;
    } else {
        float s = b_tt[j];
        for (int m = 0; m < 128; ++m) s = fmaf(W_tt[j * 128 + m], b_td[m], s);
        c_t[j] = s;
    }
}

__global__ void compose2(const float* __restrict__ W_ww, const float* __restrict__ W_wd,
                         const float* __restrict__ b_wd, const float* __restrict__ A,
                         const float* __restrict__ tmpb,
                         float* __restrict__ WcT_w, float* __restrict__ c_w)
{
    int b = blockIdx.x, j = threadIdx.x;
    if (b < 128) {
        int k = b;
        float s = 0.f;
        for (int m = 0; m < 128; ++m) s = fmaf(A[j * 128 + m], W_ww[m * 128 + k], s);
        WcT_w[k * 128 + j] = s;
    } else {
        float s = b_wd[j];
        for (int m = 0; m < 128; ++m) s = fmaf(W_wd[j * 128 + m], tmpb[m], s);
        c_w[j] = s;
    }
}

// ---------------------------------------------------------------------------
// transform: y[row] = x[row] @ Wc^T + c   (WT k-major: WT[k*128+j] = Wc[j,k])
// k-blocked by 4: per k4 per thread 4x ds_read_b32 (W) + 8x ds_read_b128 (x)
// for 32 FMAs -> ~3x fewer LDS instructions than scalar version.
// ---------------------------------------------------------------------------
__global__ __launch_bounds__(256) void transform(
    const float* __restrict__ x, const float* __restrict__ WT,
    const float* __restrict__ bias, float* __restrict__ y, int nrows)
{
    __shared__ float wtp[128 * 64];   // 32 KB: columns [pass*64, pass*64+64)
    __shared__ float xs[32 * 128];    // 16 KB: 32 rows of x
    const int tid = threadIdx.x;
    const int c   = tid & 63;
    const int rg  = tid >> 6;         // wave id, 8 rows each

    for (int pass = 0; pass < 2; ++pass) {
        __syncthreads();
        for (int i = tid; i < 128 * 16; i += 256) {
            int k  = i >> 4;
            int c4 = (i & 15) << 2;
            reinterpret_cast<float4*>(wtp)[i] =
                *reinterpret_cast<const float4*>(&WT[k * 128 + pass * 64 + c4]);
        }
        const float bc = bias[pass * 64 + c];
        __syncthreads();

        for (int tile = blockIdx.x; tile * 32 < nrows; tile += gridDim.x) {
            int base = tile * 32;
            __syncthreads();
            for (int i = tid; i < 1024; i += 256) {
                int r  = i >> 5;
                int kk = (i & 31) << 2;
                int row = base + r;
                float4 v = (row < nrows)
                    ? *reinterpret_cast<const float4*>(&x[(size_t)row * 128 + kk])
                    : float4{0.f, 0.f, 0.f, 0.f};
                reinterpret_cast<float4*>(xs)[i] = v;
            }
            __syncthreads();

            float acc[8];
#pragma unroll
            for (int i = 0; i < 8; ++i) acc[i] = bc;
            const float4* xrow4 = reinterpret_cast<const float4*>(&xs[rg * 8 * 128]);
#pragma unroll 4
            for (int k4 = 0; k4 < 32; ++k4) {
                float w0 = wtp[(k4 * 4 + 0) * 64 + c];
                float w1 = wtp[(k4 * 4 + 1) * 64 + c];
                float w2 = wtp[(k4 * 4 + 2) * 64 + c];
                float w3 = wtp[(k4 * 4 + 3) * 64 + c];
#pragma unroll
                for (int i = 0; i < 8; ++i) {
                    float4 xv = xrow4[i * 32 + k4];
                    acc[i] = fmaf(xv.x, w0, acc[i]);
                    acc[i] = fmaf(xv.y, w1, acc[i]);
                    acc[i] = fmaf(xv.z, w2, acc[i]);
                    acc[i] = fmaf(xv.w, w3, acc[i]);
                }
            }
#pragma unroll
            for (int i = 0; i < 8; ++i) {
                int row = base + rg * 8 + i;
                if (row < nrows) y[(size_t)row * 128 + pass * 64 + c] = acc[i];
            }
        }
    }
}

// ---------------------------------------------------------------------------
// CSR build: hist -> scan(A,B,C) -> scatter
// ---------------------------------------------------------------------------
__global__ void hist(const int* __restrict__ dst_ww, const int* __restrict__ dst_wt,
                     const int* __restrict__ dst_wd, const int* __restrict__ dst_td,
                     const int* __restrict__ dst_tt, unsigned* __restrict__ cnt)
{
    int g = blockIdx.x * 256 + threadIdx.x;
    if (g < E_WW)                        atomicAdd(&cnt[B_WW + dst_ww[g]], 1u);
    else if (g < E_WW + E_WT)            atomicAdd(&cnt[B_WT + dst_wt[g - E_WW]], 1u);
    else if (g < E_WW + E_WT + E_WD)     atomicAdd(&cnt[B_WD + dst_wd[g - E_WW - E_WT]], 1u);
    else if (g < E_WW + E_WT + E_WD + E_TD)
        atomicAdd(&cnt[B_TD + dst_td[g - E_WW - E_WT - E_WD]], 1u);
    else if (g < E_TOT)
        atomicAdd(&cnt[B_TT + dst_tt[g - E_WW - E_WT - E_WD - E_TD]], 1u);
}

__global__ __launch_bounds__(256) void scanA(const unsigned* __restrict__ cnt,
                                             unsigned* __restrict__ bsum)
{
    __shared__ unsigned sh[256];
    int t = threadIdx.x;
    int base = blockIdx.x * 1024 + t * 4;
    unsigned s = 0;
#pragma unroll
    for (int i = 0; i < 4; ++i) { int idx = base + i; if (idx < NSLOT) s += cnt[idx]; }
    sh[t] = s; __syncthreads();
    for (int o = 128; o > 0; o >>= 1) { if (t < o) sh[t] += sh[t + o]; __syncthreads(); }
    if (t == 0) bsum[blockIdx.x] = sh[0];
}

__global__ __launch_bounds__(256) void scanB(const unsigned* __restrict__ bsum,
                                             unsigned* __restrict__ boff)
{
    __shared__ unsigned sh[256];
    int t = threadIdx.x;
    unsigned v = (t < NBLK_SCAN) ? bsum[t] : 0u;
    sh[t] = v; __syncthreads();
    for (int o = 1; o < 256; o <<= 1) {
        unsigned x = (t >= o) ? sh[t - o] : 0u;
        __syncthreads();
        sh[t] += x;
        __syncthreads();
    }
    if (t < NBLK_SCAN) boff[t] = sh[t] - v;   // exclusive
}

__global__ __launch_bounds__(256) void scanC(const unsigned* __restrict__ cnt,
                                             const unsigned* __restrict__ boff,
                                             unsigned* __restrict__ offs,
                                             unsigned* __restrict__ curs)
{
    __shared__ unsigned sh[256];
    int t = threadIdx.x;
    int base = blockIdx.x * 1024 + t * 4;
    unsigned c[4]; unsigned s = 0;
#pragma unroll
    for (int i = 0; i < 4; ++i) {
        int idx = base + i;
        c[i] = (idx < NSLOT) ? cnt[idx] : 0u;
        s += c[i];
    }
    sh[t] = s; __syncthreads();
    for (int o = 1; o < 256; o <<= 1) {
        unsigned x = (t >= o) ? sh[t - o] : 0u;
        __syncthreads();
        sh[t] += x;
        __syncthreads();
    }
    unsigned run = boff[blockIdx.x] + sh[t] - s;
#pragma unroll
    for (int i = 0; i < 4; ++i) {
        int idx = base + i;
        if (idx < NSLOT) { offs[idx] = run; curs[idx] = run; run += c[i]; }
    }
}

__global__ void scatter(const int* __restrict__ dst_ww, const int* __restrict__ dst_wt,
                        const int* __restrict__ dst_wd, const int* __restrict__ dst_td,
                        const int* __restrict__ dst_tt,
                        unsigned* __restrict__ curs, unsigned* __restrict__ csr)
{
    int g = blockIdx.x * 256 + threadIdx.x;
    int slotidx, e;
    if (g < E_WW)                            { e = g;                          slotidx = B_WW + dst_ww[e]; }
    else if (g < E_WW + E_WT)                { e = g - E_WW;                   slotidx = B_WT + dst_wt[e]; }
    else if (g < E_WW + E_WT + E_WD)         { e = g - E_WW - E_WT;            slotidx = B_WD + dst_wd[e]; }
    else if (g < E_WW + E_WT + E_WD + E_TD)  { e = g - E_WW - E_WT - E_WD;     slotidx = B_TD + dst_td[e]; }
    else if (g < E_TOT)                      { e = g - E_WW - E_WT - E_WD - E_TD; slotidx = B_TT + dst_tt[e]; }
    else return;
    unsigned slot = atomicAdd(&curs[slotidx], 1u);
    csr[slot] = (unsigned)e;
}

// ---------------------------------------------------------------------------
// gather: 32 lanes per destination node; per-relation mean + cross-relation
// sum + relu fused; writes every d_out element exactly once. No atomics.
// ---------------------------------------------------------------------------
__device__ __forceinline__ float4 seg_mean(int slot,
                                           const unsigned* __restrict__ offs,
                                           const unsigned* __restrict__ cnt,
                                           const unsigned* __restrict__ csr,
                                           const int* __restrict__ src,
                                           const float* __restrict__ ew,
                                           const float* __restrict__ h, int d4)
{
    unsigned off = offs[slot];
    unsigned deg = cnt[slot];
    float ax = 0.f, ay = 0.f, az = 0.f, aw = 0.f;
    for (unsigned j = 0; j < deg; ++j) {
        unsigned eid = csr[off + j];
        int s = src[eid];
        float w = ew[eid];
        const float4 v = *reinterpret_cast<const float4*>(&h[(size_t)s * 128 + d4]);
        ax = fmaf(v.x, w, ax); ay = fmaf(v.y, w, ay);
        az = fmaf(v.z, w, az); aw = fmaf(v.w, w, aw);
    }
    float inv = 1.0f / (float)(deg > 1u ? deg : 1u);
    return float4{ax * inv, ay * inv, az * inv, aw * inv};
}

__global__ void gather(const unsigned* __restrict__ offs, const unsigned* __restrict__ cnt,
                       const unsigned* __restrict__ csr,
                       const int* __restrict__ src_ww, const float* __restrict__ ew_ww,
                       const int* __restrict__ src_wt, const float* __restrict__ ew_wt,
                       const int* __restrict__ src_wd, const float* __restrict__ ew_wd,
                       const int* __restrict__ src_td, const float* __restrict__ ew_td,
                       const int* __restrict__ src_tt, const float* __restrict__ ew_tt,
                       const float* __restrict__ hw, const float* __restrict__ ht,
                       float* __restrict__ out)
{
    int g = blockIdx.x * 256 + threadIdx.x;
    int n = g >> 5, d4 = (g & 31) << 2;
    if (n >= NOUT) return;
    float4 r;
    if (n < NWORD) {
        r = seg_mean(B_WW + n, offs, cnt, csr, src_ww, ew_ww, hw, d4);
    } else if (n < NWORD + NTOPIC) {
        int i = n - NWORD;
        float4 a = seg_mean(B_WT + i, offs, cnt, csr, src_wt, ew_wt, hw, d4);
        float4 b = seg_mean(B_TT + i, offs, cnt, csr, src_tt, ew_tt, ht, d4);
        r = float4{a.x + b.x, a.y + b.y, a.z + b.z, a.w + b.w};
    } else {
        int i = n - NWORD - NTOPIC;
        float4 a = seg_mean(B_WD + i, offs, cnt, csr, src_wd, ew_wd, hw, d4);
        float4 b = seg_mean(B_TD + i, offs, cnt, csr, src_td, ew_td, ht, d4);
        r = float4{a.x + b.x, a.y + b.y, a.z + b.z, a.w + b.w};
    }
    r.x = fmaxf(r.x, 0.f); r.y = fmaxf(r.y, 0.f);
    r.z = fmaxf(r.z, 0.f); r.w = fmaxf(r.w, 0.f);
    *reinterpret_cast<float4*>(&out[(size_t)n * 128 + d4]) = r;
}

extern "C" void kernel_launch(void* const* d_in, const int* in_sizes, int n_in,
                              void* d_out, int out_size, void* d_ws, size_t ws_size,
                              hipStream_t stream) {
    const float* h_word  = (const float*)d_in[0];
    const float* h_topic = (const float*)d_in[1];
    // d_in[2] = h_doc: unused (doc nodes only receive)
    const float* W_ww = (const float*)d_in[3];  const float* b_ww = (const float*)d_in[4];
    const float* W_wt = (const float*)d_in[5];  const float* b_wt = (const float*)d_in[6];
    const float* W_wd = (const float*)d_in[7];  const float* b_wd = (const float*)d_in[8];
    const float* W_td = (const float*)d_in[9];  const float* b_td = (const float*)d_in[10];
    const float* W_tt = (const float*)d_in[11]; const float* b_tt = (const float*)d_in[12];
    const int*   src_ww = (const int*)d_in[13]; const int* dst_ww = (const int*)d_in[14];
    const float* ew_ww  = (const float*)d_in[15];
    const int*   src_wt = (const int*)d_in[16]; const int* dst_wt = (const int*)d_in[17];
    const float* ew_wt  = (const float*)d_in[18];
    const int*   src_wd = (const int*)d_in[19]; const int* dst_wd = (const int*)d_in[20];
    const float* ew_wd  = (const float*)d_in[21];
    const int*   src_td = (const int*)d_in[22]; const int* dst_td = (const int*)d_in[23];
    const float* ew_td  = (const float*)d_in[24];
    const int*   src_tt = (const int*)d_in[25]; const int* dst_tt = (const int*)d_in[26];
    const float* ew_tt  = (const float*)d_in[27];

    float* out = (float*)d_out;
    float* ws  = (float*)d_ws;

    // workspace layout
    float* hw     = ws;                           // NWORD*128
    float* ht     = hw + (size_t)NWORD * 128;     // NTOPIC*128
    float* WcT_w  = ht + (size_t)NTOPIC * 128;    // 16384
    float* c_w    = WcT_w + 16384;                // 128
    float* WcT_t  = c_w + 128;                    // 16384
    float* c_t    = WcT_t + 16384;                // 128
    float* Amat   = c_t + 128;                    // 16384
    float* tmpb   = Amat + 16384;                 // 128
    unsigned* cnt  = (unsigned*)(tmpb + 128);     // NSLOT
    unsigned* offs = cnt + NSLOT;                 // NSLOT
    unsigned* curs = offs + NSLOT;                // NSLOT
    unsigned* bsum = curs + NSLOT;                // 256
    unsigned* boff = bsum + 256;                  // 256
    unsigned* csr  = boff + 256;                  // E_TOT

    hipMemsetAsync(cnt, 0, NSLOT * sizeof(unsigned), stream);

    compose1<<<258, 128, 0, stream>>>(W_ww, b_ww, W_wt, b_wt, W_wd, b_wd, W_td, b_td,
                                      W_tt, b_tt, Amat, WcT_t, tmpb, c_t);
    compose2<<<129, 128, 0, stream>>>(W_ww, W_wd, b_wd, Amat, tmpb, WcT_w, c_w);

    hist<<<(E_TOT + 255) / 256, 256, 0, stream>>>(dst_ww, dst_wt, dst_wd, dst_td, dst_tt, cnt);
    scanA<<<NBLK_SCAN, 256, 0, stream>>>(cnt, bsum);
    scanB<<<1, 256, 0, stream>>>(bsum, boff);
    scanC<<<NBLK_SCAN, 256, 0, stream>>>(cnt, boff, offs, curs);
    scatter<<<(E_TOT + 255) / 256, 256, 0, stream>>>(dst_ww, dst_wt, dst_wd, dst_td, dst_tt,
                                                     curs, csr);

    transform<<<768, 256, 0, stream>>>(h_word,  WcT_w, c_w, hw, NWORD);
    transform<<<313, 256, 0, stream>>>(h_topic, WcT_t, c_t, ht, NTOPIC);

    gather<<<(NOUT * 32 + 255) / 256, 256, 0, stream>>>(
        offs, cnt, csr,
        src_ww, ew_ww, src_wt, ew_wt, src_wd, ew_wd, src_td, ew_td, src_tt, ew_tt,
        hw, ht, out);
}

// Round 4
// 342.941 us; speedup vs baseline: 6.1622x; 1.3107x over previous
//
#include <hip/hip_runtime.h>
#include <hip/hip_bf16.h>

#define DIM 128
#define NWORD 100000
#define NTOPIC 10000
#define NDOC 50000
#define NOUT (NWORD + NTOPIC + NDOC)

#define E_WW 200000
#define E_WT 100000
#define E_WD 150000
#define E_TD 100000
#define E_TT 50000
#define E_TOT 600000

// per-(relation,dst) counter slot bases in the concatenated slot space
#define B_WW 0
#define B_WT 100000
#define B_TT 110000
#define B_WD 120000
#define B_TD 170000
#define NSLOT 220000
#define NBLK_SCAN 215   // ceil(220000/1024)

typedef __attribute__((ext_vector_type(8))) short bf16x8;
typedef __attribute__((ext_vector_type(8))) unsigned short u16x8;
typedef __attribute__((ext_vector_type(4))) float f32x4;

__device__ __forceinline__ unsigned short f2bf(float f) {
    __hip_bfloat16 h = __float2bfloat16(f);
    return __builtin_bit_cast(unsigned short, h);
}
__device__ __forceinline__ float b2f(unsigned short u) {
    return __builtin_bit_cast(float, (unsigned)u << 16);
}

// ---------------------------------------------------------------------------
// compose1 / compose2: fold chained linears into one (W,b) per node type.
// Composed weights stored bf16, col-major (Wbf[j][k] = Wc[j,k]) = MFMA B-frag
// friendly (lane reads 8 consecutive k for one col j).
// ---------------------------------------------------------------------------
__global__ void compose1(const float* __restrict__ W_ww, const float* __restrict__ b_ww,
                         const float* __restrict__ W_wt, const float* __restrict__ b_wt,
                         const float* __restrict__ W_wd, const float* __restrict__ b_wd,
                         const float* __restrict__ W_td, const float* __restrict__ b_td,
                         const float* __restrict__ W_tt, const float* __restrict__ b_tt,
                         float* __restrict__ A, unsigned short* __restrict__ Wbf_t,
                         float* __restrict__ tmpb, float* __restrict__ c_t)
{
    int b = blockIdx.x, j = threadIdx.x;
    if (b < 128) {
        float s = 0.f;
        for (int m = 0; m < 128; ++m) s = fmaf(W_wd[b * 128 + m], W_wt[m * 128 + j], s);
        A[b * 128 + j] = s;
    } else if (b < 256) {
        int k = b - 128;
        float s = 0.f;
        for (int m = 0; m < 128; ++m) s = fmaf(W_tt[j * 128 + m], W_td[m * 128 + k], s);
        Wbf_t[j * 128 + k] = f2bf(s);        // Wc_t[j,k]
    } else if (b == 256) {
        float s = b_wt[j];
        for (int m = 0; m < 128; ++m) s = fmaf(W_wt[j * 128 + m], b_ww[m], s);
        tmpb[j] = s;
    } else {
        float s = b_tt[j];
        for (int m = 0; m < 128; ++m) s = fmaf(W_tt[j * 128 + m], b_td[m], s);
        c_t[j] = s;
    }
}

__global__ void compose2(const float* __restrict__ W_ww, const float* __restrict__ W_wd,
                         const float* __restrict__ b_wd, const float* __restrict__ A,
                         const float* __restrict__ tmpb,
                         unsigned short* __restrict__ Wbf_w, float* __restrict__ c_w)
{
    int b = blockIdx.x, j = threadIdx.x;
    if (b < 128) {
        int k = b;
        float s = 0.f;
        for (int m = 0; m < 128; ++m) s = fmaf(A[j * 128 + m], W_ww[m * 128 + k], s);
        Wbf_w[j * 128 + k] = f2bf(s);        // Wc_w[j,k]
    } else {
        float s = b_wd[j];
        for (int m = 0; m < 128; ++m) s = fmaf(W_wd[j * 128 + m], tmpb[m], s);
        c_w[j] = s;
    }
}

// ---------------------------------------------------------------------------
// transform_mfma: y_bf16[row] = bf16( x[row] @ Wc^T + c )
// One 16-row tile per wave, barrier-free. B-frags (all of W) in registers.
// x staged bf16 in per-wave 4KB LDS quarter with XOR swizzle (T2) so A-frag
// ds_read_b128 is conflict-free. mfma_f32_16x16x32_bf16, fp32 accum.
// A-frag: lane l -> row l&15, k = (l>>4)*8.. ; B-frag: lane l -> col l&15.
// C/D: col = l&15, row = (l>>4)*4 + reg  [m89 verified layout].
// ---------------------------------------------------------------------------
__global__ __launch_bounds__(256) void transform_mfma(
    const float* __restrict__ x, const unsigned short* __restrict__ Wbf,
    const float* __restrict__ bias, unsigned short* __restrict__ y, int ntiles)
{
    __shared__ __attribute__((aligned(16))) unsigned short xs_all[4][16 * 128];
    const int tid = threadIdx.x;
    const int wid = tid >> 6, l = tid & 63;
    char* xs = (char*)xs_all[wid];
    const int l15 = l & 15, l4 = l >> 4;

    // load all B fragments: 8 col-groups x 4 k-steps, 16B each
    bf16x8 wf[8][4];
#pragma unroll
    for (int cg = 0; cg < 8; ++cg)
#pragma unroll
        for (int ki = 0; ki < 4; ++ki)
            wf[cg][ki] = *(const bf16x8*)&Wbf[(cg * 16 + l15) * 128 + ki * 32 + l4 * 8];

    float bj[8];
#pragma unroll
    for (int cg = 0; cg < 8; ++cg) bj[cg] = bias[cg * 16 + l15];

    const int row_s = l >> 2, ch = l & 3;   // staging: 4 lanes/row, 64B chunks

    for (int tile = blockIdx.x * 4 + wid; tile < ntiles; tile += gridDim.x * 4) {
        const size_t rb = (size_t)tile * 16;

        // stage 16 rows x 128 k (fp32 -> bf16), swizzled
        const float* xr = &x[(rb + row_s) * 128 + ch * 32];
#pragma unroll
        for (int c = 0; c < 4; ++c) {
            float4 u = *(const float4*)(xr + c * 8);
            float4 v = *(const float4*)(xr + c * 8 + 4);
            u16x8 p;
            p[0] = f2bf(u.x); p[1] = f2bf(u.y); p[2] = f2bf(u.z); p[3] = f2bf(u.w);
            p[4] = f2bf(v.x); p[5] = f2bf(v.y); p[6] = f2bf(v.z); p[7] = f2bf(v.w);
            int off = row_s * 256 + ((ch * 64 + c * 16) ^ ((row_s & 7) << 4));
            *(u16x8*)(xs + off) = p;
        }

        f32x4 acc[8];
        const f32x4 zero = {0.f, 0.f, 0.f, 0.f};
#pragma unroll
        for (int cg = 0; cg < 8; ++cg) acc[cg] = zero;

#pragma unroll
        for (int ki = 0; ki < 4; ++ki) {
            int aoff = l15 * 256 + ((ki * 64 + l4 * 16) ^ ((l15 & 7) << 4));
            bf16x8 af = *(const bf16x8*)(xs + aoff);
#pragma unroll
            for (int cg = 0; cg < 8; ++cg)
                acc[cg] = __builtin_amdgcn_mfma_f32_16x16x32_bf16(af, wf[cg][ki], acc[cg], 0, 0, 0);
        }

        unsigned short* yr = &y[(rb + l4 * 4) * 128 + l15];
#pragma unroll
        for (int cg = 0; cg < 8; ++cg)
#pragma unroll
            for (int r = 0; r < 4; ++r)
                yr[r * 128 + cg * 16] = f2bf(acc[cg][r] + bj[cg]);
    }
}

// ---------------------------------------------------------------------------
// CSR build: hist -> scan(A,B,C) -> scatter (writes fused {src, ew} records)
// ---------------------------------------------------------------------------
__global__ void hist(const int* __restrict__ dst_ww, const int* __restrict__ dst_wt,
                     const int* __restrict__ dst_wd, const int* __restrict__ dst_td,
                     const int* __restrict__ dst_tt, unsigned* __restrict__ cnt)
{
    int g = blockIdx.x * 256 + threadIdx.x;
    if (g < E_WW)                        atomicAdd(&cnt[B_WW + dst_ww[g]], 1u);
    else if (g < E_WW + E_WT)            atomicAdd(&cnt[B_WT + dst_wt[g - E_WW]], 1u);
    else if (g < E_WW + E_WT + E_WD)     atomicAdd(&cnt[B_WD + dst_wd[g - E_WW - E_WT]], 1u);
    else if (g < E_WW + E_WT + E_WD + E_TD)
        atomicAdd(&cnt[B_TD + dst_td[g - E_WW - E_WT - E_WD]], 1u);
    else if (g < E_TOT)
        atomicAdd(&cnt[B_TT + dst_tt[g - E_WW - E_WT - E_WD - E_TD]], 1u);
}

__global__ __launch_bounds__(256) void scanA(const unsigned* __restrict__ cnt,
                                             unsigned* __restrict__ bsum)
{
    __shared__ unsigned sh[256];
    int t = threadIdx.x;
    int base = blockIdx.x * 1024 + t * 4;
    unsigned s = 0;
#pragma unroll
    for (int i = 0; i < 4; ++i) { int idx = base + i; if (idx < NSLOT) s += cnt[idx]; }
    sh[t] = s; __syncthreads();
    for (int o = 128; o > 0; o >>= 1) { if (t < o) sh[t] += sh[t + o]; __syncthreads(); }
    if (t == 0) bsum[blockIdx.x] = sh[0];
}

__global__ __launch_bounds__(256) void scanB(const unsigned* __restrict__ bsum,
                                             unsigned* __restrict__ boff)
{
    __shared__ unsigned sh[256];
    int t = threadIdx.x;
    unsigned v = (t < NBLK_SCAN) ? bsum[t] : 0u;
    sh[t] = v; __syncthreads();
    for (int o = 1; o < 256; o <<= 1) {
        unsigned x = (t >= o) ? sh[t - o] : 0u;
        __syncthreads();
        sh[t] += x;
        __syncthreads();
    }
    if (t < NBLK_SCAN) boff[t] = sh[t] - v;   // exclusive
}

__global__ __launch_bounds__(256) void scanC(const unsigned* __restrict__ cnt,
                                             const unsigned* __restrict__ boff,
                                             unsigned* __restrict__ offs,
                                             unsigned* __restrict__ curs)
{
    __shared__ unsigned sh[256];
    int t = threadIdx.x;
    int base = blockIdx.x * 1024 + t * 4;
    unsigned c[4]; unsigned s = 0;
#pragma unroll
    for (int i = 0; i < 4; ++i) {
        int idx = base + i;
        c[i] = (idx < NSLOT) ? cnt[idx] : 0u;
        s += c[i];
    }
    sh[t] = s; __syncthreads();
    for (int o = 1; o < 256; o <<= 1) {
        unsigned x = (t >= o) ? sh[t - o] : 0u;
        __syncthreads();
        sh[t] += x;
        __syncthreads();
    }
    unsigned run = boff[blockIdx.x] + sh[t] - s;
#pragma unroll
    for (int i = 0; i < 4; ++i) {
        int idx = base + i;
        if (idx < NSLOT) { offs[idx] = run; curs[idx] = run; run += c[i]; }
    }
}

__global__ void scatter(const int* __restrict__ dst_ww, const int* __restrict__ dst_wt,
                        const int* __restrict__ dst_wd, const int* __restrict__ dst_td,
                        const int* __restrict__ dst_tt,
                        const int* __restrict__ src_ww, const int* __restrict__ src_wt,
                        const int* __restrict__ src_wd, const int* __restrict__ src_td,
                        const int* __restrict__ src_tt,
                        const float* __restrict__ ew_ww, const float* __restrict__ ew_wt,
                        const float* __restrict__ ew_wd, const float* __restrict__ ew_td,
                        const float* __restrict__ ew_tt,
                        unsigned* __restrict__ curs, uint2* __restrict__ se)
{
    int g = blockIdx.x * 256 + threadIdx.x;
    int slotidx, e; unsigned sv; float wv;
    if (g < E_WW)                            { e = g;                             slotidx = B_WW + dst_ww[e]; sv = src_ww[e]; wv = ew_ww[e]; }
    else if (g < E_WW + E_WT)                { e = g - E_WW;                      slotidx = B_WT + dst_wt[e]; sv = src_wt[e]; wv = ew_wt[e]; }
    else if (g < E_WW + E_WT + E_WD)         { e = g - E_WW - E_WT;               slotidx = B_WD + dst_wd[e]; sv = src_wd[e]; wv = ew_wd[e]; }
    else if (g < E_WW + E_WT + E_WD + E_TD)  { e = g - E_WW - E_WT - E_WD;        slotidx = B_TD + dst_td[e]; sv = src_td[e]; wv = ew_td[e]; }
    else if (g < E_TOT)                      { e = g - E_WW - E_WT - E_WD - E_TD; slotidx = B_TT + dst_tt[e]; sv = src_tt[e]; wv = ew_tt[e]; }
    else return;
    unsigned slot = atomicAdd(&curs[slotidx], 1u);
    se[slot] = make_uint2(sv, __builtin_bit_cast(unsigned, wv));
}

// ---------------------------------------------------------------------------
// gather: 32 lanes per destination node; bf16 h rows (8B/lane), fused
// {src,ew} records; per-relation mean + cross-relation sum + relu.
// ---------------------------------------------------------------------------
__device__ __forceinline__ float4 seg_mean_bf(int slot,
                                              const unsigned* __restrict__ offs,
                                              const unsigned* __restrict__ cnt,
                                              const uint2* __restrict__ se,
                                              const unsigned short* __restrict__ h, int d4)
{
    unsigned off = offs[slot];
    unsigned deg = cnt[slot];
    float ax = 0.f, ay = 0.f, az = 0.f, aw = 0.f;
    for (unsigned j = 0; j < deg; ++j) {
        uint2 e = se[off + j];
        float w = __builtin_bit_cast(float, e.y);
        ushort4 hv = *(const ushort4*)&h[(size_t)e.x * 128 + d4];
        ax = fmaf(b2f(hv.x), w, ax); ay = fmaf(b2f(hv.y), w, ay);
        az = fmaf(b2f(hv.z), w, az); aw = fmaf(b2f(hv.w), w, aw);
    }
    float inv = 1.0f / (float)(deg > 1u ? deg : 1u);
    return float4{ax * inv, ay * inv, az * inv, aw * inv};
}

__global__ void gather(const unsigned* __restrict__ offs, const unsigned* __restrict__ cnt,
                       const uint2* __restrict__ se,
                       const unsigned short* __restrict__ hw,
                       const unsigned short* __restrict__ ht,
                       float* __restrict__ out)
{
    int g = blockIdx.x * 256 + threadIdx.x;
    int n = g >> 5, d4 = (g & 31) << 2;
    if (n >= NOUT) return;
    float4 r;
    if (n < NWORD) {
        r = seg_mean_bf(B_WW + n, offs, cnt, se, hw, d4);
    } else if (n < NWORD + NTOPIC) {
        int i = n - NWORD;
        float4 a = seg_mean_bf(B_WT + i, offs, cnt, se, hw, d4);
        float4 b = seg_mean_bf(B_TT + i, offs, cnt, se, ht, d4);
        r = float4{a.x + b.x, a.y + b.y, a.z + b.z, a.w + b.w};
    } else {
        int i = n - NWORD - NTOPIC;
        float4 a = seg_mean_bf(B_WD + i, offs, cnt, se, hw, d4);
        float4 b = seg_mean_bf(B_TD + i, offs, cnt, se, ht, d4);
        r = float4{a.x + b.x, a.y + b.y, a.z + b.z, a.w + b.w};
    }
    r.x = fmaxf(r.x, 0.f); r.y = fmaxf(r.y, 0.f);
    r.z = fmaxf(r.z, 0.f); r.w = fmaxf(r.w, 0.f);
    *reinterpret_cast<float4*>(&out[(size_t)n * 128 + d4]) = r;
}

extern "C" void kernel_launch(void* const* d_in, const int* in_sizes, int n_in,
                              void* d_out, int out_size, void* d_ws, size_t ws_size,
                              hipStream_t stream) {
    const float* h_word  = (const float*)d_in[0];
    const float* h_topic = (const float*)d_in[1];
    // d_in[2] = h_doc: unused (doc nodes only receive)
    const float* W_ww = (const float*)d_in[3];  const float* b_ww = (const float*)d_in[4];
    const float* W_wt = (const float*)d_in[5];  const float* b_wt = (const float*)d_in[6];
    const float* W_wd = (const float*)d_in[7];  const float* b_wd = (const float*)d_in[8];
    const float* W_td = (const float*)d_in[9];  const float* b_td = (const float*)d_in[10];
    const float* W_tt = (const float*)d_in[11]; const float* b_tt = (const float*)d_in[12];
    const int*   src_ww = (const int*)d_in[13]; const int* dst_ww = (const int*)d_in[14];
    const float* ew_ww  = (const float*)d_in[15];
    const int*   src_wt = (const int*)d_in[16]; const int* dst_wt = (const int*)d_in[17];
    const float* ew_wt  = (const float*)d_in[18];
    const int*   src_wd = (const int*)d_in[19]; const int* dst_wd = (const int*)d_in[20];
    const float* ew_wd  = (const float*)d_in[21];
    const int*   src_td = (const int*)d_in[22]; const int* dst_td = (const int*)d_in[23];
    const float* ew_td  = (const float*)d_in[24];
    const int*   src_tt = (const int*)d_in[25]; const int* dst_tt = (const int*)d_in[26];
    const float* ew_tt  = (const float*)d_in[27];

    float* out = (float*)d_out;

    // workspace layout
    unsigned short* hw_bf = (unsigned short*)d_ws;            // NWORD*128
    unsigned short* ht_bf = hw_bf + (size_t)NWORD * 128;      // NTOPIC*128
    unsigned short* Wbf_w = ht_bf + (size_t)NTOPIC * 128;     // 16384
    unsigned short* Wbf_t = Wbf_w + 16384;                    // 16384
    float* fbase = (float*)(Wbf_t + 16384);
    float* c_w   = fbase;                                     // 128
    float* c_t   = c_w + 128;                                 // 128
    float* Amat  = c_t + 128;                                 // 16384
    float* tmpb  = Amat + 16384;                              // 128
    uint2* se    = (uint2*)(tmpb + 128);                      // E_TOT (8B each)
    unsigned* cnt  = (unsigned*)(se + E_TOT);                 // NSLOT
    unsigned* offs = cnt + NSLOT;                             // NSLOT
    unsigned* curs = offs + NSLOT;                            // NSLOT
    unsigned* bsum = curs + NSLOT;                            // 256
    unsigned* boff = bsum + 256;                              // 256

    hipMemsetAsync(cnt, 0, NSLOT * sizeof(unsigned), stream);

    compose1<<<258, 128, 0, stream>>>(W_ww, b_ww, W_wt, b_wt, W_wd, b_wd, W_td, b_td,
                                      W_tt, b_tt, Amat, Wbf_t, tmpb, c_t);
    compose2<<<129, 128, 0, stream>>>(W_ww, W_wd, b_wd, Amat, tmpb, Wbf_w, c_w);

    hist<<<(E_TOT + 255) / 256, 256, 0, stream>>>(dst_ww, dst_wt, dst_wd, dst_td, dst_tt, cnt);
    scanA<<<NBLK_SCAN, 256, 0, stream>>>(cnt, bsum);
    scanB<<<1, 256, 0, stream>>>(bsum, boff);
    scanC<<<NBLK_SCAN, 256, 0, stream>>>(cnt, boff, offs, curs);
    scatter<<<(E_TOT + 255) / 256, 256, 0, stream>>>(
        dst_ww, dst_wt, dst_wd, dst_td, dst_tt,
        src_ww, src_wt, src_wd, src_td, src_tt,
        ew_ww, ew_wt, ew_wd, ew_td, ew_tt, curs, se);

    transform_mfma<<<512, 256, 0, stream>>>(h_word,  Wbf_w, c_w, hw_bf, NWORD / 16);
    transform_mfma<<<80,  256, 0, stream>>>(h_topic, Wbf_t, c_t, ht_bf, NTOPIC / 16);

    gather<<<(NOUT * 32 + 255) / 256, 256, 0, stream>>>(offs, cnt, se, hw_bf, ht_bf, out);
}

// Round 5
// 312.202 us; speedup vs baseline: 6.7689x; 1.0985x over previous
//
#include <hip/hip_runtime.h>
#include <hip/hip_bf16.h>

#define DIM 128
#define NWORD 100000
#define NTOPIC 10000
#define NDOC 50000
#define NOUT (NWORD + NTOPIC + NDOC)

#define E_WW 200000
#define E_WT 100000
#define E_WD 150000
#define E_TD 100000
#define E_TT 50000
#define E_TOT 600000

// per-(relation,dst) counter slot bases in the concatenated slot space
#define B_WW 0
#define B_WT 100000
#define B_TT 110000
#define B_WD 120000
#define B_TD 170000
#define NSLOT 220000
#define NBLK_SCAN 215   // ceil(220000/1024)

typedef __attribute__((ext_vector_type(8))) short bf16x8;
typedef __attribute__((ext_vector_type(8))) unsigned short u16x8;
typedef __attribute__((ext_vector_type(4))) float f32x4;

__device__ __forceinline__ unsigned short f2bf(float f) {
    __hip_bfloat16 h = __float2bfloat16(f);
    return __builtin_bit_cast(unsigned short, h);
}
__device__ __forceinline__ float b2f(unsigned short u) {
    return __builtin_bit_cast(float, (unsigned)u << 16);
}

// ---------------------------------------------------------------------------
// compose1 / compose2: fold chained linears into one (W,b) per node type.
// Composed weights stored bf16, col-major (Wbf[j][k] = Wc[j,k]).
// ---------------------------------------------------------------------------
__global__ void compose1(const float* __restrict__ W_ww, const float* __restrict__ b_ww,
                         const float* __restrict__ W_wt, const float* __restrict__ b_wt,
                         const float* __restrict__ W_wd, const float* __restrict__ b_wd,
                         const float* __restrict__ W_td, const float* __restrict__ b_td,
                         const float* __restrict__ W_tt, const float* __restrict__ b_tt,
                         float* __restrict__ A, unsigned short* __restrict__ Wbf_t,
                         float* __restrict__ tmpb, float* __restrict__ c_t)
{
    int b = blockIdx.x, j = threadIdx.x;
    if (b < 128) {
        float s = 0.f;
        for (int m = 0; m < 128; ++m) s = fmaf(W_wd[b * 128 + m], W_wt[m * 128 + j], s);
        A[b * 128 + j] = s;
    } else if (b < 256) {
        int k = b - 128;
        float s = 0.f;
        for (int m = 0; m < 128; ++m) s = fmaf(W_tt[j * 128 + m], W_td[m * 128 + k], s);
        Wbf_t[j * 128 + k] = f2bf(s);        // Wc_t[j,k]
    } else if (b == 256) {
        float s = b_wt[j];
        for (int m = 0; m < 128; ++m) s = fmaf(W_wt[j * 128 + m], b_ww[m], s);
        tmpb[j] = s;
    } else {
        float s = b_tt[j];
        for (int m = 0; m < 128; ++m) s = fmaf(W_tt[j * 128 + m], b_td[m], s);
        c_t[j] = s;
    }
}

__global__ void compose2(const float* __restrict__ W_ww, const float* __restrict__ W_wd,
                         const float* __restrict__ b_wd, const float* __restrict__ A,
                         const float* __restrict__ tmpb,
                         unsigned short* __restrict__ Wbf_w, float* __restrict__ c_w)
{
    int b = blockIdx.x, j = threadIdx.x;
    if (b < 128) {
        int k = b;
        float s = 0.f;
        for (int m = 0; m < 128; ++m) s = fmaf(A[j * 128 + m], W_ww[m * 128 + k], s);
        Wbf_w[j * 128 + k] = f2bf(s);        // Wc_w[j,k]
    } else {
        float s = b_wd[j];
        for (int m = 0; m < 128; ++m) s = fmaf(W_wd[j * 128 + m], tmpb[m], s);
        c_w[j] = s;
    }
}

// ---------------------------------------------------------------------------
// transform_mfma: y_bf16[row] = bf16( x[row] @ Wc^T + c )
// One 16-row tile per wave, barrier-free; B-frags in registers; x staged bf16
// in per-wave 4KB LDS quarter with XOR swizzle; mfma_f32_16x16x32_bf16.
// ---------------------------------------------------------------------------
__global__ __launch_bounds__(256) void transform_mfma(
    const float* __restrict__ x, const unsigned short* __restrict__ Wbf,
    const float* __restrict__ bias, unsigned short* __restrict__ y, int ntiles)
{
    __shared__ __attribute__((aligned(16))) unsigned short xs_all[4][16 * 128];
    const int tid = threadIdx.x;
    const int wid = tid >> 6, l = tid & 63;
    char* xs = (char*)xs_all[wid];
    const int l15 = l & 15, l4 = l >> 4;

    // load all B fragments: 8 col-groups x 4 k-steps
    bf16x8 wf[8][4];
#pragma unroll
    for (int cg = 0; cg < 8; ++cg)
#pragma unroll
        for (int ki = 0; ki < 4; ++ki)
            wf[cg][ki] = *(const bf16x8*)&Wbf[(cg * 16 + l15) * 128 + ki * 32 + l4 * 8];

    float bj[8];
#pragma unroll
    for (int cg = 0; cg < 8; ++cg) bj[cg] = bias[cg * 16 + l15];

    const int row_s = l >> 2, ch = l & 3;   // staging: 4 lanes/row, 64B chunks

    for (int tile = blockIdx.x * 4 + wid; tile < ntiles; tile += gridDim.x * 4) {
        const size_t rb = (size_t)tile * 16;

        const float* xr = &x[(rb + row_s) * 128 + ch * 32];
#pragma unroll
        for (int c = 0; c < 4; ++c) {
            float4 u = *(const float4*)(xr + c * 8);
            float4 v = *(const float4*)(xr + c * 8 + 4);
            u16x8 p;
            p[0] = f2bf(u.x); p[1] = f2bf(u.y); p[2] = f2bf(u.z); p[3] = f2bf(u.w);
            p[4] = f2bf(v.x); p[5] = f2bf(v.y); p[6] = f2bf(v.z); p[7] = f2bf(v.w);
            int off = row_s * 256 + ((ch * 64 + c * 16) ^ ((row_s & 7) << 4));
            *(u16x8*)(xs + off) = p;
        }

        f32x4 acc[8];
        const f32x4 zero = {0.f, 0.f, 0.f, 0.f};
#pragma unroll
        for (int cg = 0; cg < 8; ++cg) acc[cg] = zero;

#pragma unroll
        for (int ki = 0; ki < 4; ++ki) {
            int aoff = l15 * 256 + ((ki * 64 + l4 * 16) ^ ((l15 & 7) << 4));
            bf16x8 af = *(const bf16x8*)(xs + aoff);
#pragma unroll
            for (int cg = 0; cg < 8; ++cg)
                acc[cg] = __builtin_amdgcn_mfma_f32_16x16x32_bf16(af, wf[cg][ki], acc[cg], 0, 0, 0);
        }

        unsigned short* yr = &y[(rb + l4 * 4) * 128 + l15];
#pragma unroll
        for (int cg = 0; cg < 8; ++cg)
#pragma unroll
            for (int r = 0; r < 4; ++r)
                yr[r * 128 + cg * 16] = f2bf(acc[cg][r] + bj[cg]);
    }
}

// ---------------------------------------------------------------------------
// CSR build: rank_count -> scan(A,B,C) -> place (atomic-free placement)
// ---------------------------------------------------------------------------
__global__ void rank_count(const int* __restrict__ dst_ww, const int* __restrict__ dst_wt,
                           const int* __restrict__ dst_wd, const int* __restrict__ dst_td,
                           const int* __restrict__ dst_tt,
                           unsigned* __restrict__ cnt, unsigned* __restrict__ rank)
{
    int g = blockIdx.x * 256 + threadIdx.x;
    int slotidx;
    if (g < E_WW)                            slotidx = B_WW + dst_ww[g];
    else if (g < E_WW + E_WT)                slotidx = B_WT + dst_wt[g - E_WW];
    else if (g < E_WW + E_WT + E_WD)         slotidx = B_WD + dst_wd[g - E_WW - E_WT];
    else if (g < E_WW + E_WT + E_WD + E_TD)  slotidx = B_TD + dst_td[g - E_WW - E_WT - E_WD];
    else if (g < E_TOT)                      slotidx = B_TT + dst_tt[g - E_WW - E_WT - E_WD - E_TD];
    else return;
    rank[g] = atomicAdd(&cnt[slotidx], 1u);
}

__global__ __launch_bounds__(256) void scanA(const unsigned* __restrict__ cnt,
                                             unsigned* __restrict__ bsum)
{
    __shared__ unsigned sh[256];
    int t = threadIdx.x;
    int base = blockIdx.x * 1024 + t * 4;
    unsigned s = 0;
#pragma unroll
    for (int i = 0; i < 4; ++i) { int idx = base + i; if (idx < NSLOT) s += cnt[idx]; }
    sh[t] = s; __syncthreads();
    for (int o = 128; o > 0; o >>= 1) { if (t < o) sh[t] += sh[t + o]; __syncthreads(); }
    if (t == 0) bsum[blockIdx.x] = sh[0];
}

__global__ __launch_bounds__(256) void scanB(const unsigned* __restrict__ bsum,
                                             unsigned* __restrict__ boff)
{
    __shared__ unsigned sh[256];
    int t = threadIdx.x;
    unsigned v = (t < NBLK_SCAN) ? bsum[t] : 0u;
    sh[t] = v; __syncthreads();
    for (int o = 1; o < 256; o <<= 1) {
        unsigned x = (t >= o) ? sh[t - o] : 0u;
        __syncthreads();
        sh[t] += x;
        __syncthreads();
    }
    if (t < NBLK_SCAN) boff[t] = sh[t] - v;   // exclusive
}

__global__ __launch_bounds__(256) void scanC(const unsigned* __restrict__ cnt,
                                             const unsigned* __restrict__ boff,
                                             unsigned* __restrict__ offs)
{
    __shared__ unsigned sh[256];
    int t = threadIdx.x;
    int base = blockIdx.x * 1024 + t * 4;
    unsigned c[4]; unsigned s = 0;
#pragma unroll
    for (int i = 0; i < 4; ++i) {
        int idx = base + i;
        c[i] = (idx < NSLOT) ? cnt[idx] : 0u;
        s += c[i];
    }
    sh[t] = s; __syncthreads();
    for (int o = 1; o < 256; o <<= 1) {
        unsigned x = (t >= o) ? sh[t - o] : 0u;
        __syncthreads();
        sh[t] += x;
        __syncthreads();
    }
    unsigned run = boff[blockIdx.x] + sh[t] - s;
#pragma unroll
    for (int i = 0; i < 4; ++i) {
        int idx = base + i;
        if (idx < NSLOT) {
            offs[idx] = run;
            run += c[i];
            if (idx == NSLOT - 1) offs[NSLOT] = run;
        }
    }
}

__global__ void place(const int* __restrict__ dst_ww, const int* __restrict__ dst_wt,
                      const int* __restrict__ dst_wd, const int* __restrict__ dst_td,
                      const int* __restrict__ dst_tt,
                      const int* __restrict__ src_ww, const int* __restrict__ src_wt,
                      const int* __restrict__ src_wd, const int* __restrict__ src_td,
                      const int* __restrict__ src_tt,
                      const float* __restrict__ ew_ww, const float* __restrict__ ew_wt,
                      const float* __restrict__ ew_wd, const float* __restrict__ ew_td,
                      const float* __restrict__ ew_tt,
                      const unsigned* __restrict__ offs, const unsigned* __restrict__ rank,
                      uint2* __restrict__ se)
{
    int g = blockIdx.x * 256 + threadIdx.x;
    int slotidx, e; unsigned sv; float wv;
    if (g < E_WW)                            { e = g;                             slotidx = B_WW + dst_ww[e]; sv = src_ww[e]; wv = ew_ww[e]; }
    else if (g < E_WW + E_WT)                { e = g - E_WW;                      slotidx = B_WT + dst_wt[e]; sv = src_wt[e]; wv = ew_wt[e]; }
    else if (g < E_WW + E_WT + E_WD)         { e = g - E_WW - E_WT;               slotidx = B_WD + dst_wd[e]; sv = src_wd[e]; wv = ew_wd[e]; }
    else if (g < E_WW + E_WT + E_WD + E_TD)  { e = g - E_WW - E_WT - E_WD;        slotidx = B_TD + dst_td[e]; sv = src_td[e]; wv = ew_td[e]; }
    else if (g < E_TOT)                      { e = g - E_WW - E_WT - E_WD - E_TD; slotidx = B_TT + dst_tt[e]; sv = src_tt[e]; wv = ew_tt[e]; }
    else return;
    se[offs[slotidx] + rank[g]] = make_uint2(sv, __builtin_bit_cast(unsigned, wv));
}

// ---------------------------------------------------------------------------
// gather: 32 lanes per destination node, 4-deep edge pipelining.
// Overshoot edges are masked via src=0 / w=0 (se padded by 4 records).
// ---------------------------------------------------------------------------
__device__ __forceinline__ float4 seg_mean_bf(int slot,
                                              const unsigned* __restrict__ offs,
                                              const uint2* __restrict__ se,
                                              const unsigned short* __restrict__ h, int d4)
{
    unsigned off = offs[slot];
    unsigned deg = offs[slot + 1] - off;
    float ax = 0.f, ay = 0.f, az = 0.f, aw = 0.f;
    for (unsigned j = 0; j < deg; j += 4) {
        uint2 r0 = se[off + j];
        uint2 r1 = se[off + j + 1];
        uint2 r2 = se[off + j + 2];
        uint2 r3 = se[off + j + 3];
        unsigned s0 = r0.x;
        float    w0 = __builtin_bit_cast(float, r0.y);
        unsigned s1 = (j + 1 < deg) ? r1.x : 0u;
        float    w1 = (j + 1 < deg) ? __builtin_bit_cast(float, r1.y) : 0.f;
        unsigned s2 = (j + 2 < deg) ? r2.x : 0u;
        float    w2 = (j + 2 < deg) ? __builtin_bit_cast(float, r2.y) : 0.f;
        unsigned s3 = (j + 3 < deg) ? r3.x : 0u;
        float    w3 = (j + 3 < deg) ? __builtin_bit_cast(float, r3.y) : 0.f;
        ushort4 a0 = *(const ushort4*)&h[(size_t)s0 * 128 + d4];
        ushort4 a1 = *(const ushort4*)&h[(size_t)s1 * 128 + d4];
        ushort4 a2 = *(const ushort4*)&h[(size_t)s2 * 128 + d4];
        ushort4 a3 = *(const ushort4*)&h[(size_t)s3 * 128 + d4];
        ax = fmaf(b2f(a0.x), w0, ax); ay = fmaf(b2f(a0.y), w0, ay);
        az = fmaf(b2f(a0.z), w0, az); aw = fmaf(b2f(a0.w), w0, aw);
        ax = fmaf(b2f(a1.x), w1, ax); ay = fmaf(b2f(a1.y), w1, ay);
        az = fmaf(b2f(a1.z), w1, az); aw = fmaf(b2f(a1.w), w1, aw);
        ax = fmaf(b2f(a2.x), w2, ax); ay = fmaf(b2f(a2.y), w2, ay);
        az = fmaf(b2f(a2.z), w2, az); aw = fmaf(b2f(a2.w), w2, aw);
        ax = fmaf(b2f(a3.x), w3, ax); ay = fmaf(b2f(a3.y), w3, ay);
        az = fmaf(b2f(a3.z), w3, az); aw = fmaf(b2f(a3.w), w3, aw);
    }
    float inv = 1.0f / (float)(deg > 1u ? deg : 1u);
    return float4{ax * inv, ay * inv, az * inv, aw * inv};
}

__global__ void gather(const unsigned* __restrict__ offs,
                       const uint2* __restrict__ se,
                       const unsigned short* __restrict__ hw,
                       const unsigned short* __restrict__ ht,
                       float* __restrict__ out)
{
    int g = blockIdx.x * 256 + threadIdx.x;
    int n = g >> 5, d4 = (g & 31) << 2;
    if (n >= NOUT) return;
    float4 r;
    if (n < NWORD) {
        r = seg_mean_bf(B_WW + n, offs, se, hw, d4);
    } else if (n < NWORD + NTOPIC) {
        int i = n - NWORD;
        float4 a = seg_mean_bf(B_WT + i, offs, se, hw, d4);
        float4 b = seg_mean_bf(B_TT + i, offs, se, ht, d4);
        r = float4{a.x + b.x, a.y + b.y, a.z + b.z, a.w + b.w};
    } else {
        int i = n - NWORD - NTOPIC;
        float4 a = seg_mean_bf(B_WD + i, offs, se, hw, d4);
        float4 b = seg_mean_bf(B_TD + i, offs, se, ht, d4);
        r = float4{a.x + b.x, a.y + b.y, a.z + b.z, a.w + b.w};
    }
    r.x = fmaxf(r.x, 0.f); r.y = fmaxf(r.y, 0.f);
    r.z = fmaxf(r.z, 0.f); r.w = fmaxf(r.w, 0.f);
    *reinterpret_cast<float4*>(&out[(size_t)n * 128 + d4]) = r;
}

extern "C" void kernel_launch(void* const* d_in, const int* in_sizes, int n_in,
                              void* d_out, int out_size, void* d_ws, size_t ws_size,
                              hipStream_t stream) {
    const float* h_word  = (const float*)d_in[0];
    const float* h_topic = (const float*)d_in[1];
    // d_in[2] = h_doc: unused (doc nodes only receive)
    const float* W_ww = (const float*)d_in[3];  const float* b_ww = (const float*)d_in[4];
    const float* W_wt = (const float*)d_in[5];  const float* b_wt = (const float*)d_in[6];
    const float* W_wd = (const float*)d_in[7];  const float* b_wd = (const float*)d_in[8];
    const float* W_td = (const float*)d_in[9];  const float* b_td = (const float*)d_in[10];
    const float* W_tt = (const float*)d_in[11]; const float* b_tt = (const float*)d_in[12];
    const int*   src_ww = (const int*)d_in[13]; const int* dst_ww = (const int*)d_in[14];
    const float* ew_ww  = (const float*)d_in[15];
    const int*   src_wt = (const int*)d_in[16]; const int* dst_wt = (const int*)d_in[17];
    const float* ew_wt  = (const float*)d_in[18];
    const int*   src_wd = (const int*)d_in[19]; const int* dst_wd = (const int*)d_in[20];
    const float* ew_wd  = (const float*)d_in[21];
    const int*   src_td = (const int*)d_in[22]; const int* dst_td = (const int*)d_in[23];
    const float* ew_td  = (const float*)d_in[24];
    const int*   src_tt = (const int*)d_in[25]; const int* dst_tt = (const int*)d_in[26];
    const float* ew_tt  = (const float*)d_in[27];

    float* out = (float*)d_out;

    // workspace layout
    unsigned short* hw_bf = (unsigned short*)d_ws;            // NWORD*128
    unsigned short* ht_bf = hw_bf + (size_t)NWORD * 128;      // NTOPIC*128
    unsigned short* Wbf_w = ht_bf + (size_t)NTOPIC * 128;     // 16384
    unsigned short* Wbf_t = Wbf_w + 16384;                    // 16384
    float* fbase = (float*)(Wbf_t + 16384);
    float* c_w   = fbase;                                     // 128
    float* c_t   = c_w + 128;                                 // 128
    float* Amat  = c_t + 128;                                 // 16384
    float* tmpb  = Amat + 16384;                              // 128
    uint2* se    = (uint2*)(tmpb + 128);                      // E_TOT + 4 (8B each)
    unsigned* cnt  = (unsigned*)(se + E_TOT + 4);             // NSLOT
    unsigned* offs = cnt + NSLOT;                             // NSLOT + 1
    unsigned* rank = offs + NSLOT + 1;                        // E_TOT
    unsigned* bsum = rank + E_TOT;                            // 256
    unsigned* boff = bsum + 256;                              // 256

    hipMemsetAsync(cnt, 0, NSLOT * sizeof(unsigned), stream);

    compose1<<<258, 128, 0, stream>>>(W_ww, b_ww, W_wt, b_wt, W_wd, b_wd, W_td, b_td,
                                      W_tt, b_tt, Amat, Wbf_t, tmpb, c_t);
    compose2<<<129, 128, 0, stream>>>(W_ww, W_wd, b_wd, Amat, tmpb, Wbf_w, c_w);

    rank_count<<<(E_TOT + 255) / 256, 256, 0, stream>>>(dst_ww, dst_wt, dst_wd, dst_td, dst_tt,
                                                        cnt, rank);
    scanA<<<NBLK_SCAN, 256, 0, stream>>>(cnt, bsum);
    scanB<<<1, 256, 0, stream>>>(bsum, boff);
    scanC<<<NBLK_SCAN, 256, 0, stream>>>(cnt, boff, offs);
    place<<<(E_TOT + 255) / 256, 256, 0, stream>>>(
        dst_ww, dst_wt, dst_wd, dst_td, dst_tt,
        src_ww, src_wt, src_wd, src_td, src_tt,
        ew_ww, ew_wt, ew_wd, ew_td, ew_tt, offs, rank, se);

    transform_mfma<<<512, 256, 0, stream>>>(h_word,  Wbf_w, c_w, hw_bf, NWORD / 16);
    transform_mfma<<<80,  256, 0, stream>>>(h_topic, Wbf_t, c_t, ht_bf, NTOPIC / 16);

    gather<<<(NOUT * 32 + 255) / 256, 256, 0, stream>>>(offs, se, hw_bf, ht_bf, out);
}

// Round 6
// 301.279 us; speedup vs baseline: 7.0143x; 1.0363x over previous
//
#include <hip/hip_runtime.h>
#include <hip/hip_bf16.h>

#define DIM 128
#define NWORD 100000
#define NTOPIC 10000
#define NDOC 50000
#define NOUT (NWORD + NTOPIC + NDOC)

#define E_WW 200000
#define E_WT 100000
#define E_WD 150000
#define E_TD 100000
#define E_TT 50000
#define E_TOT 600000

// per-(relation,dst) counter slot bases in the concatenated slot space
#define B_WW 0
#define B_WT 100000
#define B_TT 110000
#define B_WD 120000
#define B_TD 170000
#define NSLOT 220000
#define NBLK_SCAN 215   // ceil(220000/1024)

#define NBW 512   // transform blocks for word
#define NBT 64    // transform blocks for topic

typedef __attribute__((ext_vector_type(8))) short bf16x8;
typedef __attribute__((ext_vector_type(8))) unsigned short u16x8;
typedef __attribute__((ext_vector_type(4))) float f32x4;

__device__ __forceinline__ unsigned short f2bf(float f) {
    __hip_bfloat16 h = __float2bfloat16(f);
    return __builtin_bit_cast(unsigned short, h);
}
__device__ __forceinline__ float b2f(unsigned short u) {
    return __builtin_bit_cast(float, (unsigned)u << 16);
}

// ---------------------------------------------------------------------------
// prep1 = compose stage 1 + zero(cnt).
//   blocks 0..127   : A[r][j]     = sum_m W_wd[r,m] * W_wt[m,j]
//   blocks 128..255 : Wbf_t[j][k] = bf16( sum_m W_tt[j,m] * W_td[m,k] )
//   block 256       : tmpb[j] = W_wt@b_ww + b_wt ; block 257: c_t = W_tt@b_td + b_tt
// ---------------------------------------------------------------------------
__global__ __launch_bounds__(128) void prep1(
    const float* __restrict__ W_ww, const float* __restrict__ b_ww,
    const float* __restrict__ W_wt, const float* __restrict__ b_wt,
    const float* __restrict__ W_wd, const float* __restrict__ b_wd,
    const float* __restrict__ W_td, const float* __restrict__ b_td,
    const float* __restrict__ W_tt, const float* __restrict__ b_tt,
    float* __restrict__ A, unsigned short* __restrict__ Wbf_t,
    float* __restrict__ tmpb, float* __restrict__ c_t, unsigned* __restrict__ cnt)
{
    int b = blockIdx.x, j = threadIdx.x;
    for (int i = b * 128 + j; i < NSLOT; i += gridDim.x * 128) cnt[i] = 0u;

    if (b < 128) {
        const float* wr = &W_wd[b * 128];
        float s0 = 0.f, s1 = 0.f, s2 = 0.f, s3 = 0.f;
        for (int m = 0; m < 128; m += 4) {
            s0 = fmaf(wr[m + 0], W_wt[(m + 0) * 128 + j], s0);
            s1 = fmaf(wr[m + 1], W_wt[(m + 1) * 128 + j], s1);
            s2 = fmaf(wr[m + 2], W_wt[(m + 2) * 128 + j], s2);
            s3 = fmaf(wr[m + 3], W_wt[(m + 3) * 128 + j], s3);
        }
        A[b * 128 + j] = (s0 + s1) + (s2 + s3);
    } else if (b < 256) {
        int k = b - 128;
        const float* wr = &W_tt[j * 128];
        float s0 = 0.f, s1 = 0.f, s2 = 0.f, s3 = 0.f;
        for (int m = 0; m < 128; m += 4) {
            s0 = fmaf(wr[m + 0], W_td[(m + 0) * 128 + k], s0);
            s1 = fmaf(wr[m + 1], W_td[(m + 1) * 128 + k], s1);
            s2 = fmaf(wr[m + 2], W_td[(m + 2) * 128 + k], s2);
            s3 = fmaf(wr[m + 3], W_td[(m + 3) * 128 + k], s3);
        }
        Wbf_t[j * 128 + k] = f2bf((s0 + s1) + (s2 + s3));
    } else if (b == 256) {
        float s = b_wt[j];
        for (int m = 0; m < 128; ++m) s = fmaf(W_wt[j * 128 + m], b_ww[m], s);
        tmpb[j] = s;
    } else {
        float s = b_tt[j];
        for (int m = 0; m < 128; ++m) s = fmaf(W_tt[j * 128 + m], b_td[m], s);
        c_t[j] = s;
    }
}

// ---------------------------------------------------------------------------
// prep2 = compose stage 2 + rank_count (fused; disjoint block ranges).
//   blocks 0..63  : Wbf_w[j][k] = bf16( sum_m A[j,m] * W_ww[m,k] ), k = 2b+(tid>>7)
//   block 64      : c_w[j] = W_wd@tmpb + b_wd (threads 0..127)
//   blocks 65+    : rank[e] = atomicAdd(cnt[slot(e)], 1)
// ---------------------------------------------------------------------------
__global__ __launch_bounds__(256) void prep2(
    const float* __restrict__ W_ww, const float* __restrict__ W_wd,
    const float* __restrict__ b_wd, const float* __restrict__ A,
    const float* __restrict__ tmpb,
    unsigned short* __restrict__ Wbf_w, float* __restrict__ c_w,
    const int* __restrict__ dst_ww, const int* __restrict__ dst_wt,
    const int* __restrict__ dst_wd, const int* __restrict__ dst_td,
    const int* __restrict__ dst_tt,
    unsigned* __restrict__ cnt, unsigned* __restrict__ rank)
{
    int b = blockIdx.x, tid = threadIdx.x;
    if (b < 64) {
        int k = b * 2 + (tid >> 7), j = tid & 127;
        const float* ar = &A[j * 128];
        float s0 = 0.f, s1 = 0.f, s2 = 0.f, s3 = 0.f;
        for (int m = 0; m < 128; m += 4) {
            s0 = fmaf(ar[m + 0], W_ww[(m + 0) * 128 + k], s0);
            s1 = fmaf(ar[m + 1], W_ww[(m + 1) * 128 + k], s1);
            s2 = fmaf(ar[m + 2], W_ww[(m + 2) * 128 + k], s2);
            s3 = fmaf(ar[m + 3], W_ww[(m + 3) * 128 + k], s3);
        }
        Wbf_w[j * 128 + k] = f2bf((s0 + s1) + (s2 + s3));
    } else if (b == 64) {
        if (tid < 128) {
            float s = b_wd[tid];
            for (int m = 0; m < 128; ++m) s = fmaf(W_wd[tid * 128 + m], tmpb[m], s);
            c_w[tid] = s;
        }
    } else {
        int g = (b - 65) * 256 + tid;
        int slotidx;
        if (g < E_WW)                            slotidx = B_WW + dst_ww[g];
        else if (g < E_WW + E_WT)                slotidx = B_WT + dst_wt[g - E_WW];
        else if (g < E_WW + E_WT + E_WD)         slotidx = B_WD + dst_wd[g - E_WW - E_WT];
        else if (g < E_WW + E_WT + E_WD + E_TD)  slotidx = B_TD + dst_td[g - E_WW - E_WT - E_WD];
        else if (g < E_TOT)                      slotidx = B_TT + dst_tt[g - E_WW - E_WT - E_WD - E_TD];
        else return;
        rank[g] = atomicAdd(&cnt[slotidx], 1u);
    }
}

// ---------------------------------------------------------------------------
// transform_mfma (merged word+topic): y_bf16[row] = bf16( x[row] @ Wc^T + c )
// One 16-row tile per wave, barrier-free; B-frags in registers; x staged bf16
// in per-wave 4KB LDS quarter with XOR swizzle; software prefetch: next tile's
// global loads issued into the dead gl regs before the MFMA section.
// ---------------------------------------------------------------------------
__global__ __launch_bounds__(256) void transform_mfma(
    const float* __restrict__ xw, const unsigned short* __restrict__ Wbf_w,
    const float* __restrict__ cw, unsigned short* __restrict__ yw, int ntw,
    const float* __restrict__ xt, const unsigned short* __restrict__ Wbf_t,
    const float* __restrict__ ct, unsigned short* __restrict__ yt, int ntt)
{
    __shared__ __attribute__((aligned(16))) unsigned short xs_all[4][16 * 128];
    const int tid = threadIdx.x;
    const int wid = tid >> 6, l = tid & 63;
    char* xs = (char*)xs_all[wid];
    const int l15 = l & 15, l4 = l >> 4;

    const bool isw = blockIdx.x < NBW;
    const float* x = isw ? xw : xt;
    const unsigned short* Wbf = isw ? Wbf_w : Wbf_t;
    const float* bias = isw ? cw : ct;
    unsigned short* y = isw ? yw : yt;
    const int nt = isw ? ntw : ntt;
    const int t0 = (isw ? blockIdx.x : blockIdx.x - NBW) * 4 + wid;
    const int tstr = (isw ? NBW : NBT) * 4;

    // load all B fragments: 8 col-groups x 4 k-steps
    bf16x8 wf[8][4];
#pragma unroll
    for (int cg = 0; cg < 8; ++cg)
#pragma unroll
        for (int ki = 0; ki < 4; ++ki)
            wf[cg][ki] = *(const bf16x8*)&Wbf[(cg * 16 + l15) * 128 + ki * 32 + l4 * 8];

    float bj[8];
#pragma unroll
    for (int cg = 0; cg < 8; ++cg) bj[cg] = bias[cg * 16 + l15];

    const int row_s = l >> 2, ch = l & 3;   // staging: 4 lanes/row, 64B chunks

    float4 u[4], v[4];
    if (t0 < nt) {
        const float* xr = &x[((size_t)t0 * 16 + row_s) * 128 + ch * 32];
#pragma unroll
        for (int c = 0; c < 4; ++c) { u[c] = *(const float4*)(xr + c * 8); v[c] = *(const float4*)(xr + c * 8 + 4); }
    }

    for (int tile = t0; tile < nt; tile += tstr) {
        // stage current tile (fp32 -> bf16), swizzled
#pragma unroll
        for (int c = 0; c < 4; ++c) {
            u16x8 p;
            p[0] = f2bf(u[c].x); p[1] = f2bf(u[c].y); p[2] = f2bf(u[c].z); p[3] = f2bf(u[c].w);
            p[4] = f2bf(v[c].x); p[5] = f2bf(v[c].y); p[6] = f2bf(v[c].z); p[7] = f2bf(v[c].w);
            int off = row_s * 256 + ((ch * 64 + c * 16) ^ ((row_s & 7) << 4));
            *(u16x8*)(xs + off) = p;
        }
        // prefetch next tile into the now-dead gl regs (hides HBM latency under MFMA)
        int nxt = tile + tstr;
        if (nxt < nt) {
            const float* xr = &x[((size_t)nxt * 16 + row_s) * 128 + ch * 32];
#pragma unroll
            for (int c = 0; c < 4; ++c) { u[c] = *(const float4*)(xr + c * 8); v[c] = *(const float4*)(xr + c * 8 + 4); }
        }

        f32x4 acc[8];
        const f32x4 zero = {0.f, 0.f, 0.f, 0.f};
#pragma unroll
        for (int cg = 0; cg < 8; ++cg) acc[cg] = zero;

#pragma unroll
        for (int ki = 0; ki < 4; ++ki) {
            int aoff = l15 * 256 + ((ki * 64 + l4 * 16) ^ ((l15 & 7) << 4));
            bf16x8 af = *(const bf16x8*)(xs + aoff);
#pragma unroll
            for (int cg = 0; cg < 8; ++cg)
                acc[cg] = __builtin_amdgcn_mfma_f32_16x16x32_bf16(af, wf[cg][ki], acc[cg], 0, 0, 0);
        }

        unsigned short* yr = &y[((size_t)tile * 16 + l4 * 4) * 128 + l15];
#pragma unroll
        for (int cg = 0; cg < 8; ++cg)
#pragma unroll
            for (int r = 0; r < 4; ++r)
                yr[r * 128 + cg * 16] = f2bf(acc[cg][r] + bj[cg]);
    }
}

// ---------------------------------------------------------------------------
// scan chain: scanA (block partial sums) -> scanB (scan of partials) ->
// scanC (per-slot exclusive offsets, offs[NSLOT] = E_TOT)
// ---------------------------------------------------------------------------
__global__ __launch_bounds__(256) void scanA(const unsigned* __restrict__ cnt,
                                             unsigned* __restrict__ bsum)
{
    __shared__ unsigned sh[256];
    int t = threadIdx.x;
    int base = blockIdx.x * 1024 + t * 4;
    unsigned s = 0;
#pragma unroll
    for (int i = 0; i < 4; ++i) { int idx = base + i; if (idx < NSLOT) s += cnt[idx]; }
    sh[t] = s; __syncthreads();
    for (int o = 128; o > 0; o >>= 1) { if (t < o) sh[t] += sh[t + o]; __syncthreads(); }
    if (t == 0) bsum[blockIdx.x] = sh[0];
}

__global__ __launch_bounds__(256) void scanB(const unsigned* __restrict__ bsum,
                                             unsigned* __restrict__ boff)
{
    __shared__ unsigned sh[256];
    int t = threadIdx.x;
    unsigned v = (t < NBLK_SCAN) ? bsum[t] : 0u;
    sh[t] = v; __syncthreads();
    for (int o = 1; o < 256; o <<= 1) {
        unsigned x = (t >= o) ? sh[t - o] : 0u;
        __syncthreads();
        sh[t] += x;
        __syncthreads();
    }
    if (t < NBLK_SCAN) boff[t] = sh[t] - v;   // exclusive
}

__global__ __launch_bounds__(256) void scanC(const unsigned* __restrict__ cnt,
                                             const unsigned* __restrict__ boff,
                                             unsigned* __restrict__ offs)
{
    __shared__ unsigned sh[256];
    int t = threadIdx.x;
    int base = blockIdx.x * 1024 + t * 4;
    unsigned c[4]; unsigned s = 0;
#pragma unroll
    for (int i = 0; i < 4; ++i) {
        int idx = base + i;
        c[i] = (idx < NSLOT) ? cnt[idx] : 0u;
        s += c[i];
    }
    sh[t] = s; __syncthreads();
    for (int o = 1; o < 256; o <<= 1) {
        unsigned x = (t >= o) ? sh[t - o] : 0u;
        __syncthreads();
        sh[t] += x;
        __syncthreads();
    }
    unsigned run = boff[blockIdx.x] + sh[t] - s;
#pragma unroll
    for (int i = 0; i < 4; ++i) {
        int idx = base + i;
        if (idx < NSLOT) {
            offs[idx] = run;
            run += c[i];
            if (idx == NSLOT - 1) offs[NSLOT] = run;
        }
    }
}

// ---------------------------------------------------------------------------
// place: atomic-free CSR placement. se[offs[slot] + rank[e]] = {src, ew}
// ---------------------------------------------------------------------------
__global__ void place(const int* __restrict__ dst_ww, const int* __restrict__ dst_wt,
                      const int* __restrict__ dst_wd, const int* __restrict__ dst_td,
                      const int* __restrict__ dst_tt,
                      const int* __restrict__ src_ww, const int* __restrict__ src_wt,
                      const int* __restrict__ src_wd, const int* __restrict__ src_td,
                      const int* __restrict__ src_tt,
                      const float* __restrict__ ew_ww, const float* __restrict__ ew_wt,
                      const float* __restrict__ ew_wd, const float* __restrict__ ew_td,
                      const float* __restrict__ ew_tt,
                      const unsigned* __restrict__ offs, const unsigned* __restrict__ rank,
                      uint2* __restrict__ se)
{
    int g = blockIdx.x * 256 + threadIdx.x;
    int slotidx, e; unsigned sv; float wv;
    if (g < E_WW)                            { e = g;                             slotidx = B_WW + dst_ww[e]; sv = src_ww[e]; wv = ew_ww[e]; }
    else if (g < E_WW + E_WT)                { e = g - E_WW;                      slotidx = B_WT + dst_wt[e]; sv = src_wt[e]; wv = ew_wt[e]; }
    else if (g < E_WW + E_WT + E_WD)         { e = g - E_WW - E_WT;               slotidx = B_WD + dst_wd[e]; sv = src_wd[e]; wv = ew_wd[e]; }
    else if (g < E_WW + E_WT + E_WD + E_TD)  { e = g - E_WW - E_WT - E_WD;        slotidx = B_TD + dst_td[e]; sv = src_td[e]; wv = ew_td[e]; }
    else if (g < E_TOT)                      { e = g - E_WW - E_WT - E_WD - E_TD; slotidx = B_TT + dst_tt[e]; sv = src_tt[e]; wv = ew_tt[e]; }
    else return;
    se[offs[slotidx] + rank[g]] = make_uint2(sv, __builtin_bit_cast(unsigned, wv));
}

// ---------------------------------------------------------------------------
// gather: 32 lanes per destination node, 4-deep edge pipelining.
// Overshoot edges masked via src=0 / w=0 (se padded by 4 records).
// ---------------------------------------------------------------------------
__device__ __forceinline__ float4 seg_mean_bf(int slot,
                                              const unsigned* __restrict__ offs,
                                              const uint2* __restrict__ se,
                                              const unsigned short* __restrict__ h, int d4)
{
    unsigned off = offs[slot];
    unsigned deg = offs[slot + 1] - off;
    float ax = 0.f, ay = 0.f, az = 0.f, aw = 0.f;
    for (unsigned j = 0; j < deg; j += 4) {
        uint2 r0 = se[off + j];
        uint2 r1 = se[off + j + 1];
        uint2 r2 = se[off + j + 2];
        uint2 r3 = se[off + j + 3];
        unsigned s0 = r0.x;
        float    w0 = __builtin_bit_cast(float, r0.y);
        unsigned s1 = (j + 1 < deg) ? r1.x : 0u;
        float    w1 = (j + 1 < deg) ? __builtin_bit_cast(float, r1.y) : 0.f;
        unsigned s2 = (j + 2 < deg) ? r2.x : 0u;
        float    w2 = (j + 2 < deg) ? __builtin_bit_cast(float, r2.y) : 0.f;
        unsigned s3 = (j + 3 < deg) ? r3.x : 0u;
        float    w3 = (j + 3 < deg) ? __builtin_bit_cast(float, r3.y) : 0.f;
        ushort4 a0 = *(const ushort4*)&h[(size_t)s0 * 128 + d4];
        ushort4 a1 = *(const ushort4*)&h[(size_t)s1 * 128 + d4];
        ushort4 a2 = *(const ushort4*)&h[(size_t)s2 * 128 + d4];
        ushort4 a3 = *(const ushort4*)&h[(size_t)s3 * 128 + d4];
        ax = fmaf(b2f(a0.x), w0, ax); ay = fmaf(b2f(a0.y), w0, ay);
        az = fmaf(b2f(a0.z), w0, az); aw = fmaf(b2f(a0.w), w0, aw);
        ax = fmaf(b2f(a1.x), w1, ax); ay = fmaf(b2f(a1.y), w1, ay);
        az = fmaf(b2f(a1.z), w1, az); aw = fmaf(b2f(a1.w), w1, aw);
        ax = fmaf(b2f(a2.x), w2, ax); ay = fmaf(b2f(a2.y), w2, ay);
        az = fmaf(b2f(a2.z), w2, az); aw = fmaf(b2f(a2.w), w2, aw);
        ax = fmaf(b2f(a3.x), w3, ax); ay = fmaf(b2f(a3.y), w3, ay);
        az = fmaf(b2f(a3.z), w3, az); aw = fmaf(b2f(a3.w), w3, aw);
    }
    float inv = 1.0f / (float)(deg > 1u ? deg : 1u);
    return float4{ax * inv, ay * inv, az * inv, aw * inv};
}

__global__ void gather(const unsigned* __restrict__ offs,
                       const uint2* __restrict__ se,
                       const unsigned short* __restrict__ hw,
                       const unsigned short* __restrict__ ht,
                       float* __restrict__ out)
{
    int g = blockIdx.x * 256 + threadIdx.x;
    int n = g >> 5, d4 = (g & 31) << 2;
    if (n >= NOUT) return;
    float4 r;
    if (n < NWORD) {
        r = seg_mean_bf(B_WW + n, offs, se, hw, d4);
    } else if (n < NWORD + NTOPIC) {
        int i = n - NWORD;
        float4 a = seg_mean_bf(B_WT + i, offs, se, hw, d4);
        float4 b = seg_mean_bf(B_TT + i, offs, se, ht, d4);
        r = float4{a.x + b.x, a.y + b.y, a.z + b.z, a.w + b.w};
    } else {
        int i = n - NWORD - NTOPIC;
        float4 a = seg_mean_bf(B_WD + i, offs, se, hw, d4);
        float4 b = seg_mean_bf(B_TD + i, offs, se, ht, d4);
        r = float4{a.x + b.x, a.y + b.y, a.z + b.z, a.w + b.w};
    }
    r.x = fmaxf(r.x, 0.f); r.y = fmaxf(r.y, 0.f);
    r.z = fmaxf(r.z, 0.f); r.w = fmaxf(r.w, 0.f);
    *reinterpret_cast<float4*>(&out[(size_t)n * 128 + d4]) = r;
}

extern "C" void kernel_launch(void* const* d_in, const int* in_sizes, int n_in,
                              void* d_out, int out_size, void* d_ws, size_t ws_size,
                              hipStream_t stream) {
    const float* h_word  = (const float*)d_in[0];
    const float* h_topic = (const float*)d_in[1];
    // d_in[2] = h_doc: unused (doc nodes only receive)
    const float* W_ww = (const float*)d_in[3];  const float* b_ww = (const float*)d_in[4];
    const float* W_wt = (const float*)d_in[5];  const float* b_wt = (const float*)d_in[6];
    const float* W_wd = (const float*)d_in[7];  const float* b_wd = (const float*)d_in[8];
    const float* W_td = (const float*)d_in[9];  const float* b_td = (const float*)d_in[10];
    const float* W_tt = (const float*)d_in[11]; const float* b_tt = (const float*)d_in[12];
    const int*   src_ww = (const int*)d_in[13]; const int* dst_ww = (const int*)d_in[14];
    const float* ew_ww  = (const float*)d_in[15];
    const int*   src_wt = (const int*)d_in[16]; const int* dst_wt = (const int*)d_in[17];
    const float* ew_wt  = (const float*)d_in[18];
    const int*   src_wd = (const int*)d_in[19]; const int* dst_wd = (const int*)d_in[20];
    const float* ew_wd  = (const float*)d_in[21];
    const int*   src_td = (const int*)d_in[22]; const int* dst_td = (const int*)d_in[23];
    const float* ew_td  = (const float*)d_in[24];
    const int*   src_tt = (const int*)d_in[25]; const int* dst_tt = (const int*)d_in[26];
    const float* ew_tt  = (const float*)d_in[27];

    float* out = (float*)d_out;

    // workspace layout
    unsigned short* hw_bf = (unsigned short*)d_ws;            // NWORD*128
    unsigned short* ht_bf = hw_bf + (size_t)NWORD * 128;      // NTOPIC*128
    unsigned short* Wbf_w = ht_bf + (size_t)NTOPIC * 128;     // 16384
    unsigned short* Wbf_t = Wbf_w + 16384;                    // 16384
    float* fbase = (float*)(Wbf_t + 16384);
    float* c_w   = fbase;                                     // 128
    float* c_t   = c_w + 128;                                 // 128
    float* Amat  = c_t + 128;                                 // 16384
    float* tmpb  = Amat + 16384;                              // 128
    uint2* se    = (uint2*)(tmpb + 128);                      // E_TOT + 4 (8B each)
    unsigned* cnt  = (unsigned*)(se + E_TOT + 4);             // NSLOT
    unsigned* offs = cnt + NSLOT;                             // NSLOT + 1
    unsigned* rank = offs + NSLOT + 1;                        // E_TOT
    unsigned* bsum = rank + E_TOT;                            // 256
    unsigned* boff = bsum + 256;                              // 256

    prep1<<<258, 128, 0, stream>>>(W_ww, b_ww, W_wt, b_wt, W_wd, b_wd, W_td, b_td,
                                   W_tt, b_tt, Amat, Wbf_t, tmpb, c_t, cnt);
    prep2<<<65 + (E_TOT + 255) / 256, 256, 0, stream>>>(
        W_ww, W_wd, b_wd, Amat, tmpb, Wbf_w, c_w,
        dst_ww, dst_wt, dst_wd, dst_td, dst_tt, cnt, rank);

    scanA<<<NBLK_SCAN, 256, 0, stream>>>(cnt, bsum);
    scanB<<<1, 256, 0, stream>>>(bsum, boff);
    scanC<<<NBLK_SCAN, 256, 0, stream>>>(cnt, boff, offs);
    place<<<(E_TOT + 255) / 256, 256, 0, stream>>>(
        dst_ww, dst_wt, dst_wd, dst_td, dst_tt,
        src_ww, src_wt, src_wd, src_td, src_tt,
        ew_ww, ew_wt, ew_wd, ew_td, ew_tt, offs, rank, se);

    transform_mfma<<<NBW + NBT, 256, 0, stream>>>(
        h_word,  Wbf_w, c_w, hw_bf, NWORD / 16,
        h_topic, Wbf_t, c_t, ht_bf, NTOPIC / 16);

    gather<<<(NOUT * 32 + 255) / 256, 256, 0, stream>>>(offs, se, hw_bf, ht_bf, out);
}